// Round 1
// baseline (612.526 us; speedup 1.0000x reference)
//
#include <hip/hip_runtime.h>
#include <cstdint>

// Problem: MultiHeadSelfAttention  B=2, T=2048, HIDDEN=2048, NH=16, HD=128
// Inputs (fp32): hidden_states, attention_mask(unused: causal -1e9, applied
// analytically), position_ids(unused: == arange(T)), Wq, Wk, Wv, Wo,
// cos_cached, sin_cached. Output fp32 (2,2048,2048).
//
// Pipeline: cvt fp32->bf16 -> QKV GEMM (+RoPE epilogue, V stored transposed)
// -> flash attention (causal tile skip) -> out-proj GEMM (fp32 out).
// Workspace use: 96 MB.

typedef __bf16 v8bf __attribute__((ext_vector_type(8)));
typedef float  v4f  __attribute__((ext_vector_type(4)));

__device__ __forceinline__ uint16_t f2bf(float f) {
  union { float f; uint32_t u; } v; v.f = f;
  uint32_t u = v.u;
  return (uint16_t)((u + 0x7FFFu + ((u >> 16) & 1u)) >> 16);  // RNE
}

__device__ __forceinline__ void gload16(const void* g, void* l) {
  __builtin_amdgcn_global_load_lds(
      (const __attribute__((address_space(1))) void*)g,
      (__attribute__((address_space(3))) void*)l, 16, 0, 0);
}

// ---------------- fp32 -> bf16 conversion (vectorized) ----------------
__global__ void cvt_bf16_kernel(const float* __restrict__ src,
                                uint16_t* __restrict__ dst, int n4) {
  int i = blockIdx.x * blockDim.x + threadIdx.x;
  int stride = gridDim.x * blockDim.x;
  for (; i < n4; i += stride) {
    float4 v = reinterpret_cast<const float4*>(src)[i];
    ushort4 o;
    o.x = f2bf(v.x); o.y = f2bf(v.y); o.z = f2bf(v.z); o.w = f2bf(v.w);
    reinterpret_cast<ushort4*>(dst)[i] = o;
  }
}

// ---------------- shared 128x128 GEMM mainloop (A row-major [*,2048],
// Bt = B^T row-major [N=2048][K=2048]; C = A @ B) ----------------
__device__ __forceinline__ void gemm128_mainloop(
    const uint16_t* __restrict__ A, const uint16_t* __restrict__ Bt,
    int m0, int n0, uint16_t* As, uint16_t* Bs, v4f acc[4][4]) {
  const int tid  = threadIdx.x;
  const int lane = tid & 63;
  const int w    = tid >> 6;
  const int wr   = w >> 1, wc = w & 1;
  const int lrow = lane & 15;
  const int lk8  = (lane >> 4) * 8;

  for (int k0 = 0; k0 < 2048; k0 += 64) {
#pragma unroll
    for (int i = 0; i < 4; ++i) {          // stage A tile 128x64 bf16
      int chunk = i * 256 + tid;           // 1024 x 16B
      int row = chunk >> 3, seg = chunk & 7;
      gload16(A + (size_t)(m0 + row) * 2048 + k0 + seg * 8, As + chunk * 8);
    }
#pragma unroll
    for (int i = 0; i < 4; ++i) {          // stage B tile 128x64 bf16
      int chunk = i * 256 + tid;
      int row = chunk >> 3, seg = chunk & 7;
      gload16(Bt + (size_t)(n0 + row) * 2048 + k0 + seg * 8, Bs + chunk * 8);
    }
    __syncthreads();
#pragma unroll
    for (int ks = 0; ks < 2; ++ks) {
      v8bf af[4], bfv[4];
#pragma unroll
      for (int mf = 0; mf < 4; ++mf)
        af[mf] = *reinterpret_cast<const v8bf*>(
            As + (wr * 64 + mf * 16 + lrow) * 64 + ks * 32 + lk8);
#pragma unroll
      for (int nf = 0; nf < 4; ++nf)
        bfv[nf] = *reinterpret_cast<const v8bf*>(
            Bs + (wc * 64 + nf * 16 + lrow) * 64 + ks * 32 + lk8);
#pragma unroll
      for (int mf = 0; mf < 4; ++mf)
#pragma unroll
        for (int nf = 0; nf < 4; ++nf)
          acc[mf][nf] = __builtin_amdgcn_mfma_f32_16x16x32_bf16(
              af[mf], bfv[nf], acc[mf][nf], 0, 0, 0);
    }
    __syncthreads();
  }
}

// ---------------- QKV projection + RoPE epilogue ----------------
// which = blockIdx.z: 0->Q(rope), 1->K(rope), 2->V(transposed store)
__global__ __launch_bounds__(256) void qkv_gemm_kernel(
    const uint16_t* __restrict__ Xbf,
    const uint16_t* __restrict__ Wqb, const uint16_t* __restrict__ Wkb,
    const uint16_t* __restrict__ Wvb,
    const float* __restrict__ cosc, const float* __restrict__ sinc,
    uint16_t* __restrict__ Qh, uint16_t* __restrict__ Kh,
    uint16_t* __restrict__ Vt) {
  __shared__ uint16_t As[128 * 64];
  __shared__ uint16_t Bs[128 * 64];
  const int which = blockIdx.z;
  const uint16_t* Wb = (which == 0) ? Wqb : (which == 1) ? Wkb : Wvb;
  const int m0 = blockIdx.y * 128, n0 = blockIdx.x * 128;

  v4f acc[4][4];
#pragma unroll
  for (int i = 0; i < 4; ++i)
#pragma unroll
    for (int j = 0; j < 4; ++j) acc[i][j] = (v4f)0.0f;

  gemm128_mainloop(Xbf, Wb, m0, n0, As, Bs, acc);

  const int lane = threadIdx.x & 63;
  const int w = threadIdx.x >> 6, wr = w >> 1, wc = w & 1;
  const int lrow = lane & 15, lhi = lane >> 4;
  const int b = m0 >> 11;  // batch index (block never straddles batch)

  if (which < 2) {
    uint16_t* dst = (which == 0) ? Qh : Kh;
#pragma unroll
    for (int mf = 0; mf < 4; ++mf) {
#pragma unroll
      for (int nf = 0; nf < 4; ++nf) {
        const int n = n0 + wc * 64 + nf * 16 + lrow;
        const int head = n >> 7, d = n & 127;
#pragma unroll
        for (int r = 0; r < 4; ++r) {
          const int m = m0 + wr * 64 + mf * 16 + lhi * 4 + r;
          const int t = m & 2047;
          float v = acc[mf][nf][r];
          float p = __shfl_xor(v, 1);          // partner feature (d^1)
          float rot = (n & 1) ? p : -p;        // x_rot[2i]=-x[2i+1]; x_rot[2i+1]=x[2i]
          float cf = cosc[t * 128 + d], sf = sinc[t * 128 + d];
          dst[((size_t)(b * 16 + head) * 2048 + t) * 128 + d] =
              f2bf(v * cf + rot * sf);
        }
      }
    }
  } else {  // V: store transposed per head -> Vt[bh][d][t]
#pragma unroll
    for (int mf = 0; mf < 4; ++mf) {
#pragma unroll
      for (int nf = 0; nf < 4; ++nf) {
        const int n = n0 + wc * 64 + nf * 16 + lrow;
        const int head = n >> 7, d = n & 127;
        const int m = m0 + wr * 64 + mf * 16 + lhi * 4;
        const int t = m & 2047;
        ushort4 o;
        o.x = f2bf(acc[mf][nf][0]); o.y = f2bf(acc[mf][nf][1]);
        o.z = f2bf(acc[mf][nf][2]); o.w = f2bf(acc[mf][nf][3]);
        *reinterpret_cast<ushort4*>(
            &Vt[((size_t)(b * 16 + head) * 128 + d) * 2048 + t]) = o;
      }
    }
  }
}

// ---------------- flash attention (causal) ----------------
// grid: (qt=T/128, bh=B*NH). block 256 = 4 waves; wave owns 32 q-rows.
__global__ __launch_bounds__(256) void attn_kernel(
    const uint16_t* __restrict__ Qh, const uint16_t* __restrict__ Kh,
    const uint16_t* __restrict__ Vt, uint16_t* __restrict__ Ob) {
  __shared__ uint16_t Ks[64 * 128];   // [kcol][d]
  __shared__ uint16_t Vs[128 * 64];   // [d][t]  (V^T tile)
  __shared__ uint16_t Ps[4][32 * 64]; // per-wave P tile [qrow][kcol]

  const int qt = blockIdx.x, bh = blockIdx.y;
  const int tid = threadIdx.x, lane = tid & 63, w = tid >> 6;
  const int lrow = lane & 15, lhi = lane >> 4, lk8 = lhi * 8;
  const size_t base = (size_t)bh * 2048 * 128;
  const int qrow0 = qt * 128 + w * 32;

  // Q fragments, persistent in registers: 32 rows x 128 d per wave
  v8bf qf[2][4];
#pragma unroll
  for (int mf = 0; mf < 2; ++mf)
#pragma unroll
    for (int ks = 0; ks < 4; ++ks)
      qf[mf][ks] = *reinterpret_cast<const v8bf*>(
          Qh + base + (size_t)(qrow0 + mf * 16 + lrow) * 128 + ks * 32 + lk8);

  v4f acc_o[2][8];
#pragma unroll
  for (int i = 0; i < 2; ++i)
#pragma unroll
    for (int j = 0; j < 8; ++j) acc_o[i][j] = (v4f)0.0f;
  float mrun[2][4], lrun[2][4];
#pragma unroll
  for (int i = 0; i < 2; ++i)
#pragma unroll
    for (int r = 0; r < 4; ++r) { mrun[i][r] = -1e30f; lrun[i][r] = 0.0f; }

  const int nkt = (qt + 1) * 2;  // causal: only tiles with k <= q range
  for (int kt = 0; kt < nkt; ++kt) {
    // stage K tile [64][128]
#pragma unroll
    for (int i = 0; i < 4; ++i) {
      int chunk = i * 256 + tid;
      int row = chunk >> 4, seg = chunk & 15;
      gload16(Kh + base + (size_t)(kt * 64 + row) * 128 + seg * 8,
              Ks + chunk * 8);
    }
    // stage V^T tile [128][64]
#pragma unroll
    for (int i = 0; i < 4; ++i) {
      int chunk = i * 256 + tid;
      int row = chunk >> 3, seg = chunk & 7;
      gload16(Vt + base + (size_t)row * 2048 + kt * 64 + seg * 8,
              Vs + chunk * 8);
    }
    __syncthreads();

    // S = Q @ K^T  (32 q-rows x 64 kcols per wave)
    v4f sacc[2][4];
#pragma unroll
    for (int i = 0; i < 2; ++i)
#pragma unroll
      for (int j = 0; j < 4; ++j) sacc[i][j] = (v4f)0.0f;
#pragma unroll
    for (int ks = 0; ks < 4; ++ks) {
      v8bf bfv[4];
#pragma unroll
      for (int nf = 0; nf < 4; ++nf)
        bfv[nf] = *reinterpret_cast<const v8bf*>(
            Ks + (nf * 16 + lrow) * 128 + ks * 32 + lk8);
#pragma unroll
      for (int mf = 0; mf < 2; ++mf)
#pragma unroll
        for (int nf = 0; nf < 4; ++nf)
          sacc[mf][nf] = __builtin_amdgcn_mfma_f32_16x16x32_bf16(
              qf[mf][ks], bfv[nf], sacc[mf][nf], 0, 0, 0);
    }

    const float sc = 0.08838834764831845f;  // 1/sqrt(128)
    const bool partial = (kt >= qt * 2);
#pragma unroll
    for (int mf = 0; mf < 2; ++mf)
#pragma unroll
      for (int nf = 0; nf < 4; ++nf)
#pragma unroll
        for (int r = 0; r < 4; ++r) {
          float s = sacc[mf][nf][r] * sc;
          if (partial) {
            int qrow = qrow0 + mf * 16 + lhi * 4 + r;
            int kcol = kt * 64 + nf * 16 + lrow;
            if (kcol > qrow) s = -1e30f;
          }
          sacc[mf][nf][r] = s;
        }

    // online softmax per row (row spread across 16 lanes x 4 nf)
#pragma unroll
    for (int mf = 0; mf < 2; ++mf)
#pragma unroll
      for (int r = 0; r < 4; ++r) {
        float mx = sacc[mf][0][r];
#pragma unroll
        for (int nf = 1; nf < 4; ++nf) mx = fmaxf(mx, sacc[mf][nf][r]);
        mx = fmaxf(mx, __shfl_xor(mx, 1));
        mx = fmaxf(mx, __shfl_xor(mx, 2));
        mx = fmaxf(mx, __shfl_xor(mx, 4));
        mx = fmaxf(mx, __shfl_xor(mx, 8));
        float mnew = fmaxf(mrun[mf][r], mx);
        float so = __expf(mrun[mf][r] - mnew);
        mrun[mf][r] = mnew;
        float rs = 0.0f;
#pragma unroll
        for (int nf = 0; nf < 4; ++nf) {
          float p = __expf(sacc[mf][nf][r] - mnew);
          sacc[mf][nf][r] = p;
          rs += p;
        }
        rs += __shfl_xor(rs, 1);
        rs += __shfl_xor(rs, 2);
        rs += __shfl_xor(rs, 4);
        rs += __shfl_xor(rs, 8);
        lrun[mf][r] = lrun[mf][r] * so + rs;
#pragma unroll
        for (int nf = 0; nf < 8; ++nf) acc_o[mf][nf][r] *= so;
      }

    // P -> per-wave LDS (re-layout C-frag -> A-frag)
    uint16_t* Pw = Ps[w];
#pragma unroll
    for (int mf = 0; mf < 2; ++mf)
#pragma unroll
      for (int nf = 0; nf < 4; ++nf)
#pragma unroll
        for (int r = 0; r < 4; ++r)
          Pw[(mf * 16 + lhi * 4 + r) * 64 + nf * 16 + lrow] =
              f2bf(sacc[mf][nf][r]);

    // O += P @ V
#pragma unroll
    for (int ksp = 0; ksp < 2; ++ksp) {
      v8bf pf[2];
#pragma unroll
      for (int mf = 0; mf < 2; ++mf)
        pf[mf] = *reinterpret_cast<const v8bf*>(
            Pw + (mf * 16 + lrow) * 64 + ksp * 32 + lk8);
#pragma unroll
      for (int nf = 0; nf < 8; ++nf) {
        v8bf vv = *reinterpret_cast<const v8bf*>(
            Vs + (nf * 16 + lrow) * 64 + ksp * 32 + lk8);
#pragma unroll
        for (int mf = 0; mf < 2; ++mf)
          acc_o[mf][nf] = __builtin_amdgcn_mfma_f32_16x16x32_bf16(
              pf[mf], vv, acc_o[mf][nf], 0, 0, 0);
      }
    }
    __syncthreads();
  }

  // epilogue: normalize, write bf16 [m][h*128+d]
  const int b = bh >> 4, head = bh & 15;
#pragma unroll
  for (int mf = 0; mf < 2; ++mf)
#pragma unroll
    for (int nf = 0; nf < 8; ++nf) {
      const int d = nf * 16 + lrow;
#pragma unroll
      for (int r = 0; r < 4; ++r) {
        const int qrow = qrow0 + mf * 16 + lhi * 4 + r;
        float o = acc_o[mf][nf][r] / lrun[mf][r];
        Ob[((size_t)(b * 2048 + qrow)) * 2048 + head * 128 + d] = f2bf(o);
      }
    }
}

// ---------------- output projection (fp32 out) ----------------
__global__ __launch_bounds__(256) void out_gemm_kernel(
    const uint16_t* __restrict__ Abf, const uint16_t* __restrict__ Wob,
    float* __restrict__ out) {
  __shared__ uint16_t As[128 * 64];
  __shared__ uint16_t Bs[128 * 64];
  const int m0 = blockIdx.y * 128, n0 = blockIdx.x * 128;
  v4f acc[4][4];
#pragma unroll
  for (int i = 0; i < 4; ++i)
#pragma unroll
    for (int j = 0; j < 4; ++j) acc[i][j] = (v4f)0.0f;

  gemm128_mainloop(Abf, Wob, m0, n0, As, Bs, acc);

  const int lane = threadIdx.x & 63;
  const int w = threadIdx.x >> 6, wr = w >> 1, wc = w & 1;
  const int lrow = lane & 15, lhi = lane >> 4;
#pragma unroll
  for (int mf = 0; mf < 4; ++mf)
#pragma unroll
    for (int nf = 0; nf < 4; ++nf) {
      const int n = n0 + wc * 64 + nf * 16 + lrow;
#pragma unroll
      for (int r = 0; r < 4; ++r) {
        const int m = m0 + wr * 64 + mf * 16 + lhi * 4 + r;
        out[(size_t)m * 2048 + n] = acc[mf][nf][r];
      }
    }
}

extern "C" void kernel_launch(void* const* d_in, const int* in_sizes, int n_in,
                              void* d_out, int out_size, void* d_ws,
                              size_t ws_size, hipStream_t stream) {
  const float* hidden = (const float*)d_in[0];
  // d_in[1] = attention_mask (pure causal -1e9 -> applied analytically)
  // d_in[2] = position_ids   (== arange(T))
  const float* Wq = (const float*)d_in[3];
  const float* Wk = (const float*)d_in[4];
  const float* Wv = (const float*)d_in[5];
  const float* Wo = (const float*)d_in[6];
  const float* cosc = (const float*)d_in[7];
  const float* sinc = (const float*)d_in[8];
  float* out = (float*)d_out;

  uint16_t* Wqb = (uint16_t*)d_ws;            // 4M elem each
  uint16_t* Wkb = Wqb + 4194304;
  uint16_t* Wvb = Wkb + 4194304;
  uint16_t* Wob = Wvb + 4194304;
  uint16_t* Xbf = Wob + 4194304;              // 8M elem
  uint16_t* Qh  = Xbf + 8388608;              // (B*NH, T, HD)
  uint16_t* Kh  = Qh + 8388608;
  uint16_t* Vt  = Kh + 8388608;               // (B*NH, HD, T)
  uint16_t* Ob  = Xbf;                        // alias: X dead after QKV gemm

  cvt_bf16_kernel<<<2048, 256, 0, stream>>>(hidden, Xbf, 2097152);
  cvt_bf16_kernel<<<1024, 256, 0, stream>>>(Wq, Wqb, 1048576);
  cvt_bf16_kernel<<<1024, 256, 0, stream>>>(Wk, Wkb, 1048576);
  cvt_bf16_kernel<<<1024, 256, 0, stream>>>(Wv, Wvb, 1048576);
  cvt_bf16_kernel<<<1024, 256, 0, stream>>>(Wo, Wob, 1048576);

  qkv_gemm_kernel<<<dim3(16, 32, 3), 256, 0, stream>>>(
      Xbf, Wqb, Wkb, Wvb, cosc, sinc, Qh, Kh, Vt);

  attn_kernel<<<dim3(16, 32), 256, 0, stream>>>(Qh, Kh, Vt, Ob);

  out_gemm_kernel<<<dim3(16, 32), 256, 0, stream>>>(Ob, Wob, out);
}

// Round 2
// 602.952 us; speedup vs baseline: 1.0159x; 1.0159x over previous
//
#include <hip/hip_runtime.h>
#include <cstdint>

// MultiHeadSelfAttention  B=2, T=2048, HIDDEN=2048, NH=16, HD=128 (fp32 io)
// cvt->bf16 -> QKV GEMM(+RoPE, V transposed) -> flash attn (causal-pair
// balanced, XOR-swizzled LDS, 2-phase prefetch) -> out-proj GEMM.

typedef __bf16 v8bf __attribute__((ext_vector_type(8)));
typedef float  v4f  __attribute__((ext_vector_type(4)));

__device__ __forceinline__ uint16_t f2bf(float f) {
  union { float f; uint32_t u; } v; v.f = f;
  uint32_t u = v.u;
  return (uint16_t)((u + 0x7FFFu + ((u >> 16) & 1u)) >> 16);  // RNE
}

__device__ __forceinline__ void gload16(const void* g, void* l) {
  __builtin_amdgcn_global_load_lds(
      (const __attribute__((address_space(1))) void*)g,
      (__attribute__((address_space(3))) void*)l, 16, 0, 0);
}

// ---------------- fused fp32 -> bf16 conversion (5 tensors) ----------------
__global__ void cvt_all_kernel(const float* __restrict__ s0, uint16_t* d0,
                               const float* __restrict__ s1, uint16_t* d1,
                               const float* __restrict__ s2, uint16_t* d2,
                               const float* __restrict__ s3, uint16_t* d3,
                               const float* __restrict__ s4, uint16_t* d4) {
  const float* src; uint16_t* dst; int n4;
  switch (blockIdx.y) {
    case 0: src = s0; dst = d0; n4 = 2097152; break;
    case 1: src = s1; dst = d1; n4 = 1048576; break;
    case 2: src = s2; dst = d2; n4 = 1048576; break;
    case 3: src = s3; dst = d3; n4 = 1048576; break;
    default: src = s4; dst = d4; n4 = 1048576; break;
  }
  int i = blockIdx.x * blockDim.x + threadIdx.x;
  int stride = gridDim.x * blockDim.x;
  for (; i < n4; i += stride) {
    float4 v = reinterpret_cast<const float4*>(src)[i];
    ushort4 o;
    o.x = f2bf(v.x); o.y = f2bf(v.y); o.z = f2bf(v.z); o.w = f2bf(v.w);
    reinterpret_cast<ushort4*>(dst)[i] = o;
  }
}

// ---------------- shared 128x128 GEMM mainloop ----------------
__device__ __forceinline__ void gemm128_mainloop(
    const uint16_t* __restrict__ A, const uint16_t* __restrict__ Bt,
    int m0, int n0, uint16_t* As, uint16_t* Bs, v4f acc[4][4]) {
  const int tid  = threadIdx.x;
  const int lane = tid & 63;
  const int w    = tid >> 6;
  const int wr   = w >> 1, wc = w & 1;
  const int lrow = lane & 15;
  const int lk8  = (lane >> 4) * 8;

  for (int k0 = 0; k0 < 2048; k0 += 64) {
#pragma unroll
    for (int i = 0; i < 4; ++i) {          // stage A tile 128x64 bf16
      int chunk = i * 256 + tid;
      int row = chunk >> 3, seg = chunk & 7;
      gload16(A + (size_t)(m0 + row) * 2048 + k0 + seg * 8, As + chunk * 8);
    }
#pragma unroll
    for (int i = 0; i < 4; ++i) {          // stage B tile 128x64 bf16
      int chunk = i * 256 + tid;
      int row = chunk >> 3, seg = chunk & 7;
      gload16(Bt + (size_t)(n0 + row) * 2048 + k0 + seg * 8, Bs + chunk * 8);
    }
    __syncthreads();
#pragma unroll
    for (int ks = 0; ks < 2; ++ks) {
      v8bf af[4], bfv[4];
#pragma unroll
      for (int mf = 0; mf < 4; ++mf)
        af[mf] = *reinterpret_cast<const v8bf*>(
            As + (wr * 64 + mf * 16 + lrow) * 64 + ks * 32 + lk8);
#pragma unroll
      for (int nf = 0; nf < 4; ++nf)
        bfv[nf] = *reinterpret_cast<const v8bf*>(
            Bs + (wc * 64 + nf * 16 + lrow) * 64 + ks * 32 + lk8);
#pragma unroll
      for (int mf = 0; mf < 4; ++mf)
#pragma unroll
        for (int nf = 0; nf < 4; ++nf)
          acc[mf][nf] = __builtin_amdgcn_mfma_f32_16x16x32_bf16(
              af[mf], bfv[nf], acc[mf][nf], 0, 0, 0);
    }
    __syncthreads();
  }
}

// ---------------- QKV projection + RoPE epilogue ----------------
__global__ __launch_bounds__(256) void qkv_gemm_kernel(
    const uint16_t* __restrict__ Xbf,
    const uint16_t* __restrict__ Wqb, const uint16_t* __restrict__ Wkb,
    const uint16_t* __restrict__ Wvb,
    const float* __restrict__ cosc, const float* __restrict__ sinc,
    uint16_t* __restrict__ Qh, uint16_t* __restrict__ Kh,
    uint16_t* __restrict__ Vt) {
  __shared__ uint16_t As[128 * 64];
  __shared__ uint16_t Bs[128 * 64];
  // bijective XCD swizzle over 1536 blocks (1536 % 8 == 0, cpx = 192)
  const int id  = (blockIdx.z * 32 + blockIdx.y) * 16 + blockIdx.x;
  const int swz = (id & 7) * 192 + (id >> 3);
  const int which = swz >> 9;
  const int m0 = ((swz >> 4) & 31) * 128, n0 = (swz & 15) * 128;
  const uint16_t* Wb = (which == 0) ? Wqb : (which == 1) ? Wkb : Wvb;

  v4f acc[4][4];
#pragma unroll
  for (int i = 0; i < 4; ++i)
#pragma unroll
    for (int j = 0; j < 4; ++j) acc[i][j] = (v4f)0.0f;

  gemm128_mainloop(Xbf, Wb, m0, n0, As, Bs, acc);

  const int lane = threadIdx.x & 63;
  const int w = threadIdx.x >> 6, wr = w >> 1, wc = w & 1;
  const int lrow = lane & 15, lhi = lane >> 4;
  const int b = m0 >> 11;

  if (which < 2) {
    uint16_t* dst = (which == 0) ? Qh : Kh;
#pragma unroll
    for (int mf = 0; mf < 4; ++mf) {
#pragma unroll
      for (int nf = 0; nf < 4; ++nf) {
        const int n = n0 + wc * 64 + nf * 16 + lrow;
        const int head = n >> 7, d = n & 127;
#pragma unroll
        for (int r = 0; r < 4; ++r) {
          const int m = m0 + wr * 64 + mf * 16 + lhi * 4 + r;
          const int t = m & 2047;
          float v = acc[mf][nf][r];
          float p = __shfl_xor(v, 1);
          float rot = (n & 1) ? p : -p;
          float cf = cosc[t * 128 + d], sf = sinc[t * 128 + d];
          dst[((size_t)(b * 16 + head) * 2048 + t) * 128 + d] =
              f2bf(v * cf + rot * sf);
        }
      }
    }
  } else {  // V transposed per head -> Vt[bh][d][t]
#pragma unroll
    for (int mf = 0; mf < 4; ++mf) {
#pragma unroll
      for (int nf = 0; nf < 4; ++nf) {
        const int n = n0 + wc * 64 + nf * 16 + lrow;
        const int head = n >> 7, d = n & 127;
        const int m = m0 + wr * 64 + mf * 16 + lhi * 4;
        const int t = m & 2047;
        ushort4 o;
        o.x = f2bf(acc[mf][nf][0]); o.y = f2bf(acc[mf][nf][1]);
        o.z = f2bf(acc[mf][nf][2]); o.w = f2bf(acc[mf][nf][3]);
        *reinterpret_cast<ushort4*>(
            &Vt[((size_t)(b * 16 + head) * 128 + d) * 2048 + t]) = o;
      }
    }
  }
}

// ---------------- flash attention (causal, pair-balanced) ----------------
// grid (16 pairs, 32 bh), 256 thr = 4 waves. Block owns q-tiles p and 31-p
// (64 rows each, wave owns 16 rows of each) sharing one k-loop.
// K/V/P LDS XOR-swizzled (seg^row&7 @16B); K/V double-buffered.
__global__ __launch_bounds__(256, 2) void attn_kernel(
    const uint16_t* __restrict__ Qh, const uint16_t* __restrict__ Kh,
    const uint16_t* __restrict__ Vt, uint16_t* __restrict__ Ob) {
  __shared__ uint16_t Ks[2 * 64 * 128];
  __shared__ uint16_t Vs[2 * 128 * 64];
  __shared__ uint16_t Ps[4 * 2 * 16 * 64];

  const int pair = blockIdx.x, bh = blockIdx.y;
  const int qiA = pair, qiB = 31 - pair;
  const int tid = threadIdx.x, lane = tid & 63, w = tid >> 6;
  const int lrow = lane & 15, lhi = lane >> 4, lk8 = lhi * 8;
  const int sw = lrow & 7;              // read-side swizzle factor
  const size_t base = (size_t)bh * 2048 * 128;
  const int rowA0 = qiA * 64 + w * 16, rowB0 = qiB * 64 + w * 16;

  // persistent Q fragments (16 rows x 128d per tile per wave)
  v8bf qfA[4], qfB[4];
#pragma unroll
  for (int ks = 0; ks < 4; ++ks) {
    qfA[ks] = *reinterpret_cast<const v8bf*>(
        Qh + base + (size_t)(rowA0 + lrow) * 128 + ks * 32 + lk8);
    qfB[ks] = *reinterpret_cast<const v8bf*>(
        Qh + base + (size_t)(rowB0 + lrow) * 128 + ks * 32 + lk8);
  }

  v4f accA[8], accB[8];
  float mA[4], lA[4], mB[4], lB[4];
#pragma unroll
  for (int j = 0; j < 8; ++j) { accA[j] = (v4f)0.0f; accB[j] = (v4f)0.0f; }
#pragma unroll
  for (int r = 0; r < 4; ++r) {
    mA[r] = -1e30f; lA[r] = 0.0f; mB[r] = -1e30f; lB[r] = 0.0f;
  }

  auto stageKV = [&](int buf, int kt) {
    uint16_t* Kd = Ks + buf * 8192;
    uint16_t* Vd = Vs + buf * 8192;
#pragma unroll
    for (int i = 0; i < 4; ++i) {        // K tile [64][128], 16 segs/row
      int c = i * 256 + tid;
      int row = c >> 4, seg = c & 15;
      int sseg = seg ^ (row & 7);        // inverse-swizzled source
      gload16(Kh + base + (size_t)(kt * 64 + row) * 128 + sseg * 8,
              Kd + c * 8);
    }
#pragma unroll
    for (int i = 0; i < 4; ++i) {        // V^T tile [128][64], 8 segs/row
      int c = i * 256 + tid;
      int row = c >> 3, seg = c & 7;
      int sseg = seg ^ (row & 7);
      gload16(Vt + base + (size_t)row * 2048 + kt * 64 + sseg * 8,
              Vd + c * 8);
    }
  };

  auto computeTile = [&](const v8bf (&qf)[4], v4f (&acc)[8], float (&m)[4],
                         float (&l)[4], int row0, int qi, uint16_t* Pw,
                         const uint16_t* Kc, const uint16_t* Vc, int kt) {
    v4f sacc[4];
#pragma unroll
    for (int j = 0; j < 4; ++j) sacc[j] = (v4f)0.0f;
#pragma unroll
    for (int ks = 0; ks < 4; ++ks) {
      v8bf kf[4];
#pragma unroll
      for (int nf = 0; nf < 4; ++nf)
        kf[nf] = *reinterpret_cast<const v8bf*>(
            Kc + (nf * 16 + lrow) * 128 + (((ks * 4 + lhi) ^ sw) * 8));
#pragma unroll
      for (int nf = 0; nf < 4; ++nf)
        sacc[nf] = __builtin_amdgcn_mfma_f32_16x16x32_bf16(
            qf[ks], kf[nf], sacc[nf], 0, 0, 0);
    }

    const float sc = 0.08838834764831845f;  // 1/sqrt(128)
    const bool partial = (kt == qi);
#pragma unroll
    for (int nf = 0; nf < 4; ++nf)
#pragma unroll
      for (int r = 0; r < 4; ++r) {
        float s = sacc[nf][r] * sc;
        if (partial) {
          int qrow = row0 + lhi * 4 + r;
          int kcol = kt * 64 + nf * 16 + lrow;
          if (kcol > qrow) s = -1e30f;
        }
        sacc[nf][r] = s;
      }

#pragma unroll
    for (int r = 0; r < 4; ++r) {
      float mx = fmaxf(fmaxf(sacc[0][r], sacc[1][r]),
                       fmaxf(sacc[2][r], sacc[3][r]));
      mx = fmaxf(mx, __shfl_xor(mx, 1));
      mx = fmaxf(mx, __shfl_xor(mx, 2));
      mx = fmaxf(mx, __shfl_xor(mx, 4));
      mx = fmaxf(mx, __shfl_xor(mx, 8));
      float mnew = fmaxf(m[r], mx);
      float so = __expf(m[r] - mnew);
      m[r] = mnew;
      float rs = 0.0f;
#pragma unroll
      for (int nf = 0; nf < 4; ++nf) {
        float p = __expf(sacc[nf][r] - mnew);
        sacc[nf][r] = p;
        rs += p;
      }
      rs += __shfl_xor(rs, 1);
      rs += __shfl_xor(rs, 2);
      rs += __shfl_xor(rs, 4);
      rs += __shfl_xor(rs, 8);
      l[r] = l[r] * so + rs;
#pragma unroll
      for (int nf = 0; nf < 8; ++nf) acc[nf][r] *= so;
    }

    // P -> per-wave LDS (swizzled write), then PV
#pragma unroll
    for (int nf = 0; nf < 4; ++nf)
#pragma unroll
      for (int r = 0; r < 4; ++r) {
        int prow = lhi * 4 + r;
        int pcol = nf * 16 + lrow;
        Pw[prow * 64 + (pcol ^ ((prow & 7) * 8))] = f2bf(sacc[nf][r]);
      }
#pragma unroll
    for (int ksp = 0; ksp < 2; ++ksp) {
      v8bf pf = *reinterpret_cast<const v8bf*>(
          Pw + lrow * 64 + (((ksp * 4 + lhi) ^ sw) * 8));
#pragma unroll
      for (int nf = 0; nf < 8; ++nf) {
        v8bf vv = *reinterpret_cast<const v8bf*>(
            Vc + (nf * 16 + lrow) * 64 + (((ksp * 4 + lhi) ^ sw) * 8));
        acc[nf] = __builtin_amdgcn_mfma_f32_16x16x32_bf16(pf, vv, acc[nf],
                                                          0, 0, 0);
      }
    }
  };

  const int nkt = qiB + 1;  // tile A's k-range (0..qiA) is a prefix
  stageKV(0, 0);
  for (int kt = 0; kt < nkt; ++kt) {
    const int cur = kt & 1;
    __syncthreads();  // buf[cur] staged; buf[cur^1] reads (kt-1) drained
    if (kt + 1 < nkt) stageKV(cur ^ 1, kt + 1);
    const uint16_t* Kc = Ks + cur * 8192;
    const uint16_t* Vc = Vs + cur * 8192;
    computeTile(qfB, accB, mB, lB, rowB0, qiB, Ps + (w * 2 + 1) * 1024, Kc,
                Vc, kt);
    if (kt <= qiA)
      computeTile(qfA, accA, mA, lA, rowA0, qiA, Ps + (w * 2 + 0) * 1024, Kc,
                  Vc, kt);
  }

  // epilogue: normalize, write bf16 [m][head*128+d]
  const int b = bh >> 4, head = bh & 15;
#pragma unroll
  for (int nf = 0; nf < 8; ++nf) {
    const int d = head * 128 + nf * 16 + lrow;
#pragma unroll
    for (int r = 0; r < 4; ++r) {
      const int qA = rowA0 + lhi * 4 + r;
      const int qB = rowB0 + lhi * 4 + r;
      Ob[((size_t)(b * 2048 + qA)) * 2048 + d] = f2bf(accA[nf][r] / lA[r]);
      Ob[((size_t)(b * 2048 + qB)) * 2048 + d] = f2bf(accB[nf][r] / lB[r]);
    }
  }
}

// ---------------- output projection (fp32 out) ----------------
__global__ __launch_bounds__(256) void out_gemm_kernel(
    const uint16_t* __restrict__ Abf, const uint16_t* __restrict__ Wob,
    float* __restrict__ out) {
  __shared__ uint16_t As[128 * 64];
  __shared__ uint16_t Bs[128 * 64];
  const int id  = blockIdx.y * 16 + blockIdx.x;       // 512 blocks, cpx=64
  const int swz = (id & 7) * 64 + (id >> 3);
  const int m0 = (swz >> 4) * 128, n0 = (swz & 15) * 128;
  v4f acc[4][4];
#pragma unroll
  for (int i = 0; i < 4; ++i)
#pragma unroll
    for (int j = 0; j < 4; ++j) acc[i][j] = (v4f)0.0f;

  gemm128_mainloop(Abf, Wob, m0, n0, As, Bs, acc);

  const int lane = threadIdx.x & 63;
  const int w = threadIdx.x >> 6, wr = w >> 1, wc = w & 1;
  const int lrow = lane & 15, lhi = lane >> 4;
#pragma unroll
  for (int mf = 0; mf < 4; ++mf)
#pragma unroll
    for (int nf = 0; nf < 4; ++nf) {
      const int n = n0 + wc * 64 + nf * 16 + lrow;
#pragma unroll
      for (int r = 0; r < 4; ++r) {
        const int m = m0 + wr * 64 + mf * 16 + lhi * 4 + r;
        out[(size_t)m * 2048 + n] = acc[mf][nf][r];
      }
    }
}

extern "C" void kernel_launch(void* const* d_in, const int* in_sizes, int n_in,
                              void* d_out, int out_size, void* d_ws,
                              size_t ws_size, hipStream_t stream) {
  const float* hidden = (const float*)d_in[0];
  const float* Wq = (const float*)d_in[3];
  const float* Wk = (const float*)d_in[4];
  const float* Wv = (const float*)d_in[5];
  const float* Wo = (const float*)d_in[6];
  const float* cosc = (const float*)d_in[7];
  const float* sinc = (const float*)d_in[8];
  float* out = (float*)d_out;

  uint16_t* Wqb = (uint16_t*)d_ws;
  uint16_t* Wkb = Wqb + 4194304;
  uint16_t* Wvb = Wkb + 4194304;
  uint16_t* Wob = Wvb + 4194304;
  uint16_t* Xbf = Wob + 4194304;
  uint16_t* Qh  = Xbf + 8388608;
  uint16_t* Kh  = Qh + 8388608;
  uint16_t* Vt  = Kh + 8388608;
  uint16_t* Ob  = Xbf;  // X dead after QKV gemm

  cvt_all_kernel<<<dim3(512, 5), 256, 0, stream>>>(
      hidden, Xbf, Wq, Wqb, Wk, Wkb, Wv, Wvb, Wo, Wob);

  qkv_gemm_kernel<<<dim3(16, 32, 3), 256, 0, stream>>>(
      Xbf, Wqb, Wkb, Wvb, cosc, sinc, Qh, Kh, Vt);

  attn_kernel<<<dim3(16, 32), 256, 0, stream>>>(Qh, Kh, Vt, Ob);

  out_gemm_kernel<<<dim3(16, 32), 256, 0, stream>>>(Ob, Wob, out);
}

// Round 3
// 435.768 us; speedup vs baseline: 1.4056x; 1.3837x over previous
//
#include <hip/hip_runtime.h>
#include <cstdint>

// MultiHeadSelfAttention  B=2, T=2048, HIDDEN=2048, NH=16, HD=128 (fp32 io)
// cvt->bf16 -> QKV GEMM(+RoPE, V transposed) -> flash attn (swapped-QK^T,
// in-register softmax, cvt_pk+permlane P, defer-max) -> out-proj GEMM.

typedef __bf16 v8bf __attribute__((ext_vector_type(8)));
typedef float  v4f  __attribute__((ext_vector_type(4)));
typedef float  f32x16 __attribute__((ext_vector_type(16)));

__device__ __forceinline__ uint16_t f2bf(float f) {
  union { float f; uint32_t u; } v; v.f = f;
  uint32_t u = v.u;
  return (uint16_t)((u + 0x7FFFu + ((u >> 16) & 1u)) >> 16);  // RNE
}

__device__ __forceinline__ uint32_t cvtpk(float lo, float hi) {
  uint32_t w;
  asm("v_cvt_pk_bf16_f32 %0, %1, %2" : "=v"(w) : "v"(lo), "v"(hi));
  return w;
}

__device__ __forceinline__ void gload16(const void* g, void* l) {
  __builtin_amdgcn_global_load_lds(
      (const __attribute__((address_space(1))) void*)g,
      (__attribute__((address_space(3))) void*)l, 16, 0, 0);
}

// ---------------- fused fp32 -> bf16 conversion (5 tensors) ----------------
__global__ void cvt_all_kernel(const float* __restrict__ s0, uint16_t* d0,
                               const float* __restrict__ s1, uint16_t* d1,
                               const float* __restrict__ s2, uint16_t* d2,
                               const float* __restrict__ s3, uint16_t* d3,
                               const float* __restrict__ s4, uint16_t* d4) {
  const float* src; uint16_t* dst; int n4;
  switch (blockIdx.y) {
    case 0: src = s0; dst = d0; n4 = 2097152; break;
    case 1: src = s1; dst = d1; n4 = 1048576; break;
    case 2: src = s2; dst = d2; n4 = 1048576; break;
    case 3: src = s3; dst = d3; n4 = 1048576; break;
    default: src = s4; dst = d4; n4 = 1048576; break;
  }
  int i = blockIdx.x * blockDim.x + threadIdx.x;
  int stride = gridDim.x * blockDim.x;
  for (; i < n4; i += stride) {
    float4 v = reinterpret_cast<const float4*>(src)[i];
    ushort4 o;
    o.x = f2bf(v.x); o.y = f2bf(v.y); o.z = f2bf(v.z); o.w = f2bf(v.w);
    reinterpret_cast<ushort4*>(dst)[i] = o;
  }
}

// ---------------- shared 128x128 GEMM mainloop ----------------
__device__ __forceinline__ void gemm128_mainloop(
    const uint16_t* __restrict__ A, const uint16_t* __restrict__ Bt,
    int m0, int n0, uint16_t* As, uint16_t* Bs, v4f acc[4][4]) {
  const int tid  = threadIdx.x;
  const int lane = tid & 63;
  const int w    = tid >> 6;
  const int wr   = w >> 1, wc = w & 1;
  const int lrow = lane & 15;
  const int lk8  = (lane >> 4) * 8;

  for (int k0 = 0; k0 < 2048; k0 += 64) {
#pragma unroll
    for (int i = 0; i < 4; ++i) {          // stage A tile 128x64 bf16
      int chunk = i * 256 + tid;
      int row = chunk >> 3, seg = chunk & 7;
      gload16(A + (size_t)(m0 + row) * 2048 + k0 + seg * 8, As + chunk * 8);
    }
#pragma unroll
    for (int i = 0; i < 4; ++i) {          // stage B tile 128x64 bf16
      int chunk = i * 256 + tid;
      int row = chunk >> 3, seg = chunk & 7;
      gload16(Bt + (size_t)(n0 + row) * 2048 + k0 + seg * 8, Bs + chunk * 8);
    }
    __syncthreads();
#pragma unroll
    for (int ks = 0; ks < 2; ++ks) {
      v8bf af[4], bfv[4];
#pragma unroll
      for (int mf = 0; mf < 4; ++mf)
        af[mf] = *reinterpret_cast<const v8bf*>(
            As + (wr * 64 + mf * 16 + lrow) * 64 + ks * 32 + lk8);
#pragma unroll
      for (int nf = 0; nf < 4; ++nf)
        bfv[nf] = *reinterpret_cast<const v8bf*>(
            Bs + (wc * 64 + nf * 16 + lrow) * 64 + ks * 32 + lk8);
#pragma unroll
      for (int mf = 0; mf < 4; ++mf)
#pragma unroll
        for (int nf = 0; nf < 4; ++nf)
          acc[mf][nf] = __builtin_amdgcn_mfma_f32_16x16x32_bf16(
              af[mf], bfv[nf], acc[mf][nf], 0, 0, 0);
    }
    __syncthreads();
  }
}

// ---------------- QKV projection + RoPE epilogue ----------------
__global__ __launch_bounds__(256) void qkv_gemm_kernel(
    const uint16_t* __restrict__ Xbf,
    const uint16_t* __restrict__ Wqb, const uint16_t* __restrict__ Wkb,
    const uint16_t* __restrict__ Wvb,
    const float* __restrict__ cosc, const float* __restrict__ sinc,
    uint16_t* __restrict__ Qh, uint16_t* __restrict__ Kh,
    uint16_t* __restrict__ Vt) {
  __shared__ uint16_t As[128 * 64];
  __shared__ uint16_t Bs[128 * 64];
  const int id  = (blockIdx.z * 32 + blockIdx.y) * 16 + blockIdx.x;
  const int swz = (id & 7) * 192 + (id >> 3);
  const int which = swz >> 9;
  const int m0 = ((swz >> 4) & 31) * 128, n0 = (swz & 15) * 128;
  const uint16_t* Wb = (which == 0) ? Wqb : (which == 1) ? Wkb : Wvb;

  v4f acc[4][4];
#pragma unroll
  for (int i = 0; i < 4; ++i)
#pragma unroll
    for (int j = 0; j < 4; ++j) acc[i][j] = (v4f)0.0f;

  gemm128_mainloop(Xbf, Wb, m0, n0, As, Bs, acc);

  const int lane = threadIdx.x & 63;
  const int w = threadIdx.x >> 6, wr = w >> 1, wc = w & 1;
  const int lrow = lane & 15, lhi = lane >> 4;
  const int b = m0 >> 11;

  if (which < 2) {
    uint16_t* dst = (which == 0) ? Qh : Kh;
#pragma unroll
    for (int mf = 0; mf < 4; ++mf) {
#pragma unroll
      for (int nf = 0; nf < 4; ++nf) {
        const int n = n0 + wc * 64 + nf * 16 + lrow;
        const int head = n >> 7, d = n & 127;
#pragma unroll
        for (int r = 0; r < 4; ++r) {
          const int m = m0 + wr * 64 + mf * 16 + lhi * 4 + r;
          const int t = m & 2047;
          float v = acc[mf][nf][r];
          float p = __shfl_xor(v, 1);
          float rot = (n & 1) ? p : -p;
          float cf = cosc[t * 128 + d], sf = sinc[t * 128 + d];
          dst[((size_t)(b * 16 + head) * 2048 + t) * 128 + d] =
              f2bf(v * cf + rot * sf);
        }
      }
    }
  } else {  // V transposed per head -> Vt[bh][d][t]
#pragma unroll
    for (int mf = 0; mf < 4; ++mf) {
#pragma unroll
      for (int nf = 0; nf < 4; ++nf) {
        const int n = n0 + wc * 64 + nf * 16 + lrow;
        const int head = n >> 7, d = n & 127;
        const int m = m0 + wr * 64 + mf * 16 + lhi * 4;
        const int t = m & 2047;
        ushort4 o;
        o.x = f2bf(acc[mf][nf][0]); o.y = f2bf(acc[mf][nf][1]);
        o.z = f2bf(acc[mf][nf][2]); o.w = f2bf(acc[mf][nf][3]);
        *reinterpret_cast<ushort4*>(
            &Vt[((size_t)(b * 16 + head) * 128 + d) * 2048 + t]) = o;
      }
    }
  }
}

// ---------------- flash attention (swapped QK^T, in-reg softmax) ----------
// 512 blocks x 256 thr (4 waves). Block = 128 q-rows of one bh; wave = 32
// rows; lane owns ONE q-row (col of S^T). K-range = 2(qt+1) tiles of 64.
// Blocks id and id+256 have complementary qt so per-CU load balances.
__global__ __launch_bounds__(256, 2) void attn_kernel(
    const uint16_t* __restrict__ Qh, const uint16_t* __restrict__ Kh,
    const uint16_t* __restrict__ Vt, uint16_t* __restrict__ Ob) {
  __shared__ uint16_t Ks[2 * 64 * 128];
  __shared__ uint16_t Vs[2 * 128 * 64];

  const int id = blockIdx.x;
  const int qt = (id < 256) ? (15 - (id >> 5)) : ((id - 256) >> 5);
  const int bh = id & 31;
  const int tid = threadIdx.x, lane = tid & 63, w = tid >> 6;
  const int l31 = lane & 31, hi = lane >> 5;
  const size_t base = (size_t)bh * 2048 * 128;
  const int q0 = qt * 128 + w * 32;
  const int qr = q0 + l31;

  // Q as persistent B-fragments: qf[ks] = Q[qr][ks*16 + hi*8 .. +8]
  v8bf qf[8];
#pragma unroll
  for (int ks = 0; ks < 8; ++ks)
    qf[ks] = *reinterpret_cast<const v8bf*>(
        Qh + base + (size_t)qr * 128 + ks * 16 + hi * 8);

  f32x16 acc[4];  // O^T: acc[dblk], d = dblk*32 + (reg&3)+8*(reg>>2)+4*hi
#pragma unroll
  for (int d = 0; d < 4; ++d) acc[d] = (f32x16)0.0f;
  float m = -1e30f, l = 0.0f;

  auto stage = [&](int buf, int kt) {
    uint16_t* Kd = Ks + buf * 8192;
    uint16_t* Vd = Vs + buf * 8192;
#pragma unroll
    for (int i = 0; i < 4; ++i) {        // K tile [64][128], 16 segs/row
      int c = i * 256 + tid;
      int row = c >> 4, seg = c & 15;
      int sseg = seg ^ (row & 7);        // inverse-swizzled global source
      gload16(Kh + base + (size_t)(kt * 64 + row) * 128 + sseg * 8,
              Kd + c * 8);
    }
#pragma unroll
    for (int i = 0; i < 4; ++i) {        // V^T tile [128][64], 8 segs/row
      int c = i * 256 + tid;
      int row = c >> 3, seg = c & 7;
      int sseg = seg ^ (row & 7);
      gload16(Vt + base + (size_t)row * 2048 + kt * 64 + sseg * 8,
              Vd + c * 8);
    }
  };

  const float sc = 0.08838834764831845f;  // 1/sqrt(128)
  const int nkt = 2 * (qt + 1);
  stage(0, 0);
  for (int kt = 0; kt < nkt; ++kt) {
    const int cur = kt & 1;
    __syncthreads();                      // buf[cur] staged; cur^1 free
    if (kt + 1 < nkt) stage(cur ^ 1, kt + 1);
    const uint16_t* Kc = Ks + cur * 8192;
    const uint16_t* Vc = Vs + cur * 8192;

    if (kt * 64 <= q0 + 31) {            // wave-uniform: any valid kcol?
      // ---- S^T = K_tile @ Q^T : lane owns qrow qr, 32 kcols ----
      f32x16 s[2];
      s[0] = (f32x16)0.0f; s[1] = (f32x16)0.0f;
#pragma unroll
      for (int kb = 0; kb < 2; ++kb) {
        const int row = kb * 32 + l31;
        const int swz = row & 7;
#pragma unroll
        for (int ks = 0; ks < 8; ++ks) {
          const int seg = (ks * 2 + hi) ^ swz;
          v8bf kf = *reinterpret_cast<const v8bf*>(Kc + row * 128 + seg * 8);
          s[kb] = __builtin_amdgcn_mfma_f32_32x32x16_bf16(kf, qf[ks], s[kb],
                                                          0, 0, 0);
        }
      }
      // ---- scale + causal mask ----
      if (kt * 64 + 63 > q0) {           // partial tile (wave-uniform)
#pragma unroll
        for (int kb = 0; kb < 2; ++kb)
#pragma unroll
          for (int q = 0; q < 4; ++q)
#pragma unroll
            for (int r = 0; r < 4; ++r) {
              const int kc = kt * 64 + kb * 32 + q * 8 + hi * 4 + r;
              float v = s[kb][q * 4 + r] * sc;
              s[kb][q * 4 + r] = (kc > qr) ? -1e30f : v;
            }
      } else {
#pragma unroll
        for (int kb = 0; kb < 2; ++kb)
#pragma unroll
          for (int g = 0; g < 16; ++g) s[kb][g] *= sc;
      }
      // ---- row max (in-register tree + one cross-half shfl) ----
      float t8[8];
#pragma unroll
      for (int g = 0; g < 8; ++g)
        t8[g] = fmaxf(fmaxf(s[0][g], s[0][g + 8]),
                      fmaxf(s[1][g], s[1][g + 8]));
      float mx = fmaxf(fmaxf(fmaxf(t8[0], t8[1]), fmaxf(t8[2], t8[3])),
                       fmaxf(fmaxf(t8[4], t8[5]), fmaxf(t8[6], t8[7])));
      mx = fmaxf(mx, __shfl_xor(mx, 32));
      // ---- defer-max rescale (T13, THR=8) ----
      if (!__all(mx - m <= 8.0f)) {
        const float mnew = fmaxf(m, mx);
        const float so = __expf(m - mnew);
        m = mnew;
        l *= so;
#pragma unroll
        for (int d = 0; d < 4; ++d)
#pragma unroll
          for (int g = 0; g < 16; ++g) acc[d][g] *= so;
      }
      // ---- p = exp(s - m), row sum ----
      float rs = 0.0f;
#pragma unroll
      for (int kb = 0; kb < 2; ++kb)
#pragma unroll
        for (int g = 0; g < 16; ++g) {
          const float pv = __expf(s[kb][g] - m);
          s[kb][g] = pv;
          rs += pv;
        }
      rs += __shfl_xor(rs, 32);
      l += rs;
      // ---- pack P -> PV B-fragments (cvt_pk + permlane32_swap) ----
      union BW { uint32_t w[4]; v8bf v; };
      BW pb[4];
#pragma unroll
      for (int kb = 0; kb < 2; ++kb)
#pragma unroll
        for (int sl = 0; sl < 2; ++sl) {
          uint32_t a0 = cvtpk(s[kb][8 * sl + 0], s[kb][8 * sl + 1]);
          uint32_t a1 = cvtpk(s[kb][8 * sl + 2], s[kb][8 * sl + 3]);
          uint32_t b0 = cvtpk(s[kb][8 * sl + 4], s[kb][8 * sl + 5]);
          uint32_t b1 = cvtpk(s[kb][8 * sl + 6], s[kb][8 * sl + 7]);
          asm("v_permlane32_swap_b32 %0, %1" : "+v"(a0), "+v"(b0));
          asm("v_permlane32_swap_b32 %0, %1" : "+v"(a1), "+v"(b1));
          BW& f = pb[kb * 2 + sl];
          f.w[0] = a0; f.w[1] = a1; f.w[2] = b0; f.w[3] = b1;
        }
      // ---- O^T += V^T_tile @ P^T ----
#pragma unroll
      for (int d = 0; d < 4; ++d) {
        const int row = d * 32 + l31;
        const int swz = row & 7;
#pragma unroll
        for (int sl4 = 0; sl4 < 4; ++sl4) {
          const int seg = (sl4 * 2 + hi) ^ swz;
          v8bf va = *reinterpret_cast<const v8bf*>(Vc + row * 64 + seg * 8);
          acc[d] = __builtin_amdgcn_mfma_f32_32x32x16_bf16(va, pb[sl4].v,
                                                           acc[d], 0, 0, 0);
        }
      }
    }
  }

  // ---- epilogue: normalize, write bf16 (paired 4B stores) ----
  const int b = bh >> 4, head = bh & 15;
  const float inv = 1.0f / l;
#pragma unroll
  for (int d = 0; d < 4; ++d)
#pragma unroll
    for (int q = 0; q < 4; ++q)
#pragma unroll
      for (int rp = 0; rp < 2; ++rp) {
        const int dd = d * 32 + q * 8 + hi * 4 + rp * 2;
        const uint32_t lo16 = f2bf(acc[d][q * 4 + rp * 2] * inv);
        const uint32_t hi16 = f2bf(acc[d][q * 4 + rp * 2 + 1] * inv);
        *reinterpret_cast<uint32_t*>(
            &Ob[((size_t)(b * 2048 + qr)) * 2048 + head * 128 + dd]) =
            lo16 | (hi16 << 16);
      }
}

// ---------------- output projection (fp32 out) ----------------
__global__ __launch_bounds__(256) void out_gemm_kernel(
    const uint16_t* __restrict__ Abf, const uint16_t* __restrict__ Wob,
    float* __restrict__ out) {
  __shared__ uint16_t As[128 * 64];
  __shared__ uint16_t Bs[128 * 64];
  const int id  = blockIdx.y * 16 + blockIdx.x;
  const int swz = (id & 7) * 64 + (id >> 3);
  const int m0 = (swz >> 4) * 128, n0 = (swz & 15) * 128;
  v4f acc[4][4];
#pragma unroll
  for (int i = 0; i < 4; ++i)
#pragma unroll
    for (int j = 0; j < 4; ++j) acc[i][j] = (v4f)0.0f;

  gemm128_mainloop(Abf, Wob, m0, n0, As, Bs, acc);

  const int lane = threadIdx.x & 63;
  const int w = threadIdx.x >> 6, wr = w >> 1, wc = w & 1;
  const int lrow = lane & 15, lhi = lane >> 4;
#pragma unroll
  for (int mf = 0; mf < 4; ++mf)
#pragma unroll
    for (int nf = 0; nf < 4; ++nf) {
      const int n = n0 + wc * 64 + nf * 16 + lrow;
#pragma unroll
      for (int r = 0; r < 4; ++r) {
        const int m = m0 + wr * 64 + mf * 16 + lhi * 4 + r;
        out[(size_t)m * 2048 + n] = acc[mf][nf][r];
      }
    }
}

extern "C" void kernel_launch(void* const* d_in, const int* in_sizes, int n_in,
                              void* d_out, int out_size, void* d_ws,
                              size_t ws_size, hipStream_t stream) {
  const float* hidden = (const float*)d_in[0];
  const float* Wq = (const float*)d_in[3];
  const float* Wk = (const float*)d_in[4];
  const float* Wv = (const float*)d_in[5];
  const float* Wo = (const float*)d_in[6];
  const float* cosc = (const float*)d_in[7];
  const float* sinc = (const float*)d_in[8];
  float* out = (float*)d_out;

  uint16_t* Wqb = (uint16_t*)d_ws;
  uint16_t* Wkb = Wqb + 4194304;
  uint16_t* Wvb = Wkb + 4194304;
  uint16_t* Wvb2 = Wvb;  // (naming convenience)
  uint16_t* Wob = Wvb + 4194304;
  uint16_t* Xbf = Wob + 4194304;
  uint16_t* Qh  = Xbf + 8388608;
  uint16_t* Kh  = Qh + 8388608;
  uint16_t* Vt  = Kh + 8388608;
  uint16_t* Ob  = Xbf;  // X dead after QKV gemm
  (void)Wvb2;

  cvt_all_kernel<<<dim3(512, 5), 256, 0, stream>>>(
      hidden, Xbf, Wq, Wqb, Wk, Wkb, Wv, Wvb, Wo, Wob);

  qkv_gemm_kernel<<<dim3(16, 32, 3), 256, 0, stream>>>(
      Xbf, Wqb, Wkb, Wvb, cosc, sinc, Qh, Kh, Vt);

  attn_kernel<<<dim3(512), 256, 0, stream>>>(Qh, Kh, Vt, Ob);

  out_gemm_kernel<<<dim3(16, 32), 256, 0, stream>>>(Ob, Wob, out);
}

// Round 4
// 408.857 us; speedup vs baseline: 1.4981x; 1.0658x over previous
//
#include <hip/hip_runtime.h>
#include <cstdint>

// MultiHeadSelfAttention  B=2, T=2048, HIDDEN=2048, NH=16, HD=128 (fp32 io)
// cvt->bf16 -> QKV GEMM(+RoPE, V transposed) -> flash attn (swapped-QK^T,
// in-register softmax, cvt_pk+permlane P, defer-max) -> out-proj GEMM.
// R4: GEMM mainloop now double-buffered (1 barrier/K-tile, stage-ahead) with
// XOR-swizzled LDS (seg^row&7 @16B, inverse-swizzled global source).

typedef __bf16 v8bf __attribute__((ext_vector_type(8)));
typedef float  v4f  __attribute__((ext_vector_type(4)));
typedef float  f32x16 __attribute__((ext_vector_type(16)));

__device__ __forceinline__ uint16_t f2bf(float f) {
  union { float f; uint32_t u; } v; v.f = f;
  uint32_t u = v.u;
  return (uint16_t)((u + 0x7FFFu + ((u >> 16) & 1u)) >> 16);  // RNE
}

__device__ __forceinline__ uint32_t cvtpk(float lo, float hi) {
  uint32_t w;
  asm("v_cvt_pk_bf16_f32 %0, %1, %2" : "=v"(w) : "v"(lo), "v"(hi));
  return w;
}

__device__ __forceinline__ void gload16(const void* g, void* l) {
  __builtin_amdgcn_global_load_lds(
      (const __attribute__((address_space(1))) void*)g,
      (__attribute__((address_space(3))) void*)l, 16, 0, 0);
}

// ---------------- fused fp32 -> bf16 conversion (5 tensors) ----------------
__global__ void cvt_all_kernel(const float* __restrict__ s0, uint16_t* d0,
                               const float* __restrict__ s1, uint16_t* d1,
                               const float* __restrict__ s2, uint16_t* d2,
                               const float* __restrict__ s3, uint16_t* d3,
                               const float* __restrict__ s4, uint16_t* d4) {
  const float* src; uint16_t* dst; int n4;
  switch (blockIdx.y) {
    case 0: src = s0; dst = d0; n4 = 2097152; break;
    case 1: src = s1; dst = d1; n4 = 1048576; break;
    case 2: src = s2; dst = d2; n4 = 1048576; break;
    case 3: src = s3; dst = d3; n4 = 1048576; break;
    default: src = s4; dst = d4; n4 = 1048576; break;
  }
  int i = blockIdx.x * blockDim.x + threadIdx.x;
  int stride = gridDim.x * blockDim.x;
  for (; i < n4; i += stride) {
    float4 v = reinterpret_cast<const float4*>(src)[i];
    ushort4 o;
    o.x = f2bf(v.x); o.y = f2bf(v.y); o.z = f2bf(v.z); o.w = f2bf(v.w);
    reinterpret_cast<ushort4*>(dst)[i] = o;
  }
}

// ------- 128x128 GEMM mainloop: dbuf, 1 barrier/K-tile, swizzled LDS -------
// As/Bs are 2*128*64 uint16 each (64 KB total).
__device__ __forceinline__ void gemm128_mainloop(
    const uint16_t* __restrict__ A, const uint16_t* __restrict__ Bt,
    int m0, int n0, uint16_t* As, uint16_t* Bs, v4f acc[4][4]) {
  const int tid  = threadIdx.x;
  const int lane = tid & 63;
  const int w    = tid >> 6;
  const int wr   = w >> 1, wc = w & 1;
  const int lrow = lane & 15;
  const int lhi  = lane >> 4;

  auto stage = [&](int buf, int k0) {
    uint16_t* Ad = As + buf * 8192;
    uint16_t* Bd = Bs + buf * 8192;
#pragma unroll
    for (int i = 0; i < 4; ++i) {          // A tile 128x64, 8 segs/row
      int c = i * 256 + tid;
      int row = c >> 3, seg = c & 7;
      int sseg = seg ^ (row & 7);          // inverse-swizzled global source
      gload16(A + (size_t)(m0 + row) * 2048 + k0 + sseg * 8, Ad + c * 8);
    }
#pragma unroll
    for (int i = 0; i < 4; ++i) {          // B tile 128x64
      int c = i * 256 + tid;
      int row = c >> 3, seg = c & 7;
      int sseg = seg ^ (row & 7);
      gload16(Bt + (size_t)(n0 + row) * 2048 + k0 + sseg * 8, Bd + c * 8);
    }
  };

  stage(0, 0);
  for (int t = 0; t < 32; ++t) {
    __syncthreads();  // drains vmcnt (buf[t&1] staged) + lgkmcnt (old reads)
    if (t + 1 < 32) stage((t + 1) & 1, (t + 1) * 64);
    const uint16_t* Ac = As + (t & 1) * 8192;
    const uint16_t* Bc = Bs + (t & 1) * 8192;
#pragma unroll
    for (int ks = 0; ks < 2; ++ks) {
      v8bf af[4], bfv[4];
#pragma unroll
      for (int mf = 0; mf < 4; ++mf) {
        const int ar = wr * 64 + mf * 16 + lrow;
        const int seg = (ks * 4 + lhi) ^ (ar & 7);   // swizzled read
        af[mf] = *reinterpret_cast<const v8bf*>(Ac + ar * 64 + seg * 8);
      }
#pragma unroll
      for (int nf = 0; nf < 4; ++nf) {
        const int br = wc * 64 + nf * 16 + lrow;
        const int seg = (ks * 4 + lhi) ^ (br & 7);
        bfv[nf] = *reinterpret_cast<const v8bf*>(Bc + br * 64 + seg * 8);
      }
#pragma unroll
      for (int mf = 0; mf < 4; ++mf)
#pragma unroll
        for (int nf = 0; nf < 4; ++nf)
          acc[mf][nf] = __builtin_amdgcn_mfma_f32_16x16x32_bf16(
              af[mf], bfv[nf], acc[mf][nf], 0, 0, 0);
    }
  }
}

// ---------------- QKV projection + RoPE epilogue ----------------
__global__ __launch_bounds__(256, 2) void qkv_gemm_kernel(
    const uint16_t* __restrict__ Xbf,
    const uint16_t* __restrict__ Wqb, const uint16_t* __restrict__ Wkb,
    const uint16_t* __restrict__ Wvb,
    const float* __restrict__ cosc, const float* __restrict__ sinc,
    uint16_t* __restrict__ Qh, uint16_t* __restrict__ Kh,
    uint16_t* __restrict__ Vt) {
  __shared__ uint16_t As[2 * 128 * 64];
  __shared__ uint16_t Bs[2 * 128 * 64];
  const int id  = (blockIdx.z * 32 + blockIdx.y) * 16 + blockIdx.x;
  const int swz = (id & 7) * 192 + (id >> 3);
  const int which = swz >> 9;
  const int m0 = ((swz >> 4) & 31) * 128, n0 = (swz & 15) * 128;
  const uint16_t* Wb = (which == 0) ? Wqb : (which == 1) ? Wkb : Wvb;

  v4f acc[4][4];
#pragma unroll
  for (int i = 0; i < 4; ++i)
#pragma unroll
    for (int j = 0; j < 4; ++j) acc[i][j] = (v4f)0.0f;

  gemm128_mainloop(Xbf, Wb, m0, n0, As, Bs, acc);

  const int lane = threadIdx.x & 63;
  const int w = threadIdx.x >> 6, wr = w >> 1, wc = w & 1;
  const int lrow = lane & 15, lhi = lane >> 4;
  const int b = m0 >> 11;

  if (which < 2) {
    uint16_t* dst = (which == 0) ? Qh : Kh;
#pragma unroll
    for (int mf = 0; mf < 4; ++mf) {
#pragma unroll
      for (int nf = 0; nf < 4; ++nf) {
        const int n = n0 + wc * 64 + nf * 16 + lrow;
        const int head = n >> 7, d = n & 127;
#pragma unroll
        for (int r = 0; r < 4; ++r) {
          const int m = m0 + wr * 64 + mf * 16 + lhi * 4 + r;
          const int t = m & 2047;
          float v = acc[mf][nf][r];
          float p = __shfl_xor(v, 1);
          float rot = (n & 1) ? p : -p;
          float cf = cosc[t * 128 + d], sf = sinc[t * 128 + d];
          dst[((size_t)(b * 16 + head) * 2048 + t) * 128 + d] =
              f2bf(v * cf + rot * sf);
        }
      }
    }
  } else {  // V transposed per head -> Vt[bh][d][t]
#pragma unroll
    for (int mf = 0; mf < 4; ++mf) {
#pragma unroll
      for (int nf = 0; nf < 4; ++nf) {
        const int n = n0 + wc * 64 + nf * 16 + lrow;
        const int head = n >> 7, d = n & 127;
        const int m = m0 + wr * 64 + mf * 16 + lhi * 4;
        const int t = m & 2047;
        ushort4 o;
        o.x = f2bf(acc[mf][nf][0]); o.y = f2bf(acc[mf][nf][1]);
        o.z = f2bf(acc[mf][nf][2]); o.w = f2bf(acc[mf][nf][3]);
        *reinterpret_cast<ushort4*>(
            &Vt[((size_t)(b * 16 + head) * 128 + d) * 2048 + t]) = o;
      }
    }
  }
}

// ---------------- flash attention (swapped QK^T, in-reg softmax) ----------
// 512 blocks x 256 thr (4 waves). Block = 128 q-rows of one bh; wave = 32
// rows; lane owns ONE q-row (col of S^T). K-range = 2(qt+1) tiles of 64.
// Blocks id and id+256 have complementary qt so per-CU load balances.
__global__ __launch_bounds__(256, 2) void attn_kernel(
    const uint16_t* __restrict__ Qh, const uint16_t* __restrict__ Kh,
    const uint16_t* __restrict__ Vt, uint16_t* __restrict__ Ob) {
  __shared__ uint16_t Ks[2 * 64 * 128];
  __shared__ uint16_t Vs[2 * 128 * 64];

  const int id = blockIdx.x;
  const int qt = (id < 256) ? (15 - (id >> 5)) : ((id - 256) >> 5);
  const int bh = id & 31;
  const int tid = threadIdx.x, lane = tid & 63, w = tid >> 6;
  const int l31 = lane & 31, hi = lane >> 5;
  const size_t base = (size_t)bh * 2048 * 128;
  const int q0 = qt * 128 + w * 32;
  const int qr = q0 + l31;

  // Q as persistent B-fragments: qf[ks] = Q[qr][ks*16 + hi*8 .. +8]
  v8bf qf[8];
#pragma unroll
  for (int ks = 0; ks < 8; ++ks)
    qf[ks] = *reinterpret_cast<const v8bf*>(
        Qh + base + (size_t)qr * 128 + ks * 16 + hi * 8);

  f32x16 acc[4];  // O^T: acc[dblk], d = dblk*32 + (reg&3)+8*(reg>>2)+4*hi
#pragma unroll
  for (int d = 0; d < 4; ++d) acc[d] = (f32x16)0.0f;
  float m = -1e30f, l = 0.0f;

  auto stage = [&](int buf, int kt) {
    uint16_t* Kd = Ks + buf * 8192;
    uint16_t* Vd = Vs + buf * 8192;
#pragma unroll
    for (int i = 0; i < 4; ++i) {        // K tile [64][128], 16 segs/row
      int c = i * 256 + tid;
      int row = c >> 4, seg = c & 15;
      int sseg = seg ^ (row & 7);        // inverse-swizzled global source
      gload16(Kh + base + (size_t)(kt * 64 + row) * 128 + sseg * 8,
              Kd + c * 8);
    }
#pragma unroll
    for (int i = 0; i < 4; ++i) {        // V^T tile [128][64], 8 segs/row
      int c = i * 256 + tid;
      int row = c >> 3, seg = c & 7;
      int sseg = seg ^ (row & 7);
      gload16(Vt + base + (size_t)row * 2048 + kt * 64 + sseg * 8,
              Vd + c * 8);
    }
  };

  const float sc = 0.08838834764831845f;  // 1/sqrt(128)
  const int nkt = 2 * (qt + 1);
  stage(0, 0);
  for (int kt = 0; kt < nkt; ++kt) {
    const int cur = kt & 1;
    __syncthreads();                      // buf[cur] staged; cur^1 free
    if (kt + 1 < nkt) stage(cur ^ 1, kt + 1);
    const uint16_t* Kc = Ks + cur * 8192;
    const uint16_t* Vc = Vs + cur * 8192;

    if (kt * 64 <= q0 + 31) {            // wave-uniform: any valid kcol?
      // ---- S^T = K_tile @ Q^T : lane owns qrow qr, 32 kcols ----
      f32x16 s[2];
      s[0] = (f32x16)0.0f; s[1] = (f32x16)0.0f;
#pragma unroll
      for (int kb = 0; kb < 2; ++kb) {
        const int row = kb * 32 + l31;
        const int swz = row & 7;
#pragma unroll
        for (int ks = 0; ks < 8; ++ks) {
          const int seg = (ks * 2 + hi) ^ swz;
          v8bf kf = *reinterpret_cast<const v8bf*>(Kc + row * 128 + seg * 8);
          s[kb] = __builtin_amdgcn_mfma_f32_32x32x16_bf16(kf, qf[ks], s[kb],
                                                          0, 0, 0);
        }
      }
      // ---- scale + causal mask ----
      if (kt * 64 + 63 > q0) {           // partial tile (wave-uniform)
#pragma unroll
        for (int kb = 0; kb < 2; ++kb)
#pragma unroll
          for (int q = 0; q < 4; ++q)
#pragma unroll
            for (int r = 0; r < 4; ++r) {
              const int kc = kt * 64 + kb * 32 + q * 8 + hi * 4 + r;
              float v = s[kb][q * 4 + r] * sc;
              s[kb][q * 4 + r] = (kc > qr) ? -1e30f : v;
            }
      } else {
#pragma unroll
        for (int kb = 0; kb < 2; ++kb)
#pragma unroll
          for (int g = 0; g < 16; ++g) s[kb][g] *= sc;
      }
      // ---- row max (in-register tree + one cross-half shfl) ----
      float t8[8];
#pragma unroll
      for (int g = 0; g < 8; ++g)
        t8[g] = fmaxf(fmaxf(s[0][g], s[0][g + 8]),
                      fmaxf(s[1][g], s[1][g + 8]));
      float mx = fmaxf(fmaxf(fmaxf(t8[0], t8[1]), fmaxf(t8[2], t8[3])),
                       fmaxf(fmaxf(t8[4], t8[5]), fmaxf(t8[6], t8[7])));
      mx = fmaxf(mx, __shfl_xor(mx, 32));
      // ---- defer-max rescale (T13, THR=8) ----
      if (!__all(mx - m <= 8.0f)) {
        const float mnew = fmaxf(m, mx);
        const float so = __expf(m - mnew);
        m = mnew;
        l *= so;
#pragma unroll
        for (int d = 0; d < 4; ++d)
#pragma unroll
          for (int g = 0; g < 16; ++g) acc[d][g] *= so;
      }
      // ---- p = exp(s - m), row sum ----
      float rs = 0.0f;
#pragma unroll
      for (int kb = 0; kb < 2; ++kb)
#pragma unroll
        for (int g = 0; g < 16; ++g) {
          const float pv = __expf(s[kb][g] - m);
          s[kb][g] = pv;
          rs += pv;
        }
      rs += __shfl_xor(rs, 32);
      l += rs;
      // ---- pack P -> PV B-fragments (cvt_pk + permlane32_swap) ----
      union BW { uint32_t w[4]; v8bf v; };
      BW pb[4];
#pragma unroll
      for (int kb = 0; kb < 2; ++kb)
#pragma unroll
        for (int sl = 0; sl < 2; ++sl) {
          uint32_t a0 = cvtpk(s[kb][8 * sl + 0], s[kb][8 * sl + 1]);
          uint32_t a1 = cvtpk(s[kb][8 * sl + 2], s[kb][8 * sl + 3]);
          uint32_t b0 = cvtpk(s[kb][8 * sl + 4], s[kb][8 * sl + 5]);
          uint32_t b1 = cvtpk(s[kb][8 * sl + 6], s[kb][8 * sl + 7]);
          asm("v_permlane32_swap_b32 %0, %1" : "+v"(a0), "+v"(b0));
          asm("v_permlane32_swap_b32 %0, %1" : "+v"(a1), "+v"(b1));
          BW& f = pb[kb * 2 + sl];
          f.w[0] = a0; f.w[1] = a1; f.w[2] = b0; f.w[3] = b1;
        }
      // ---- O^T += V^T_tile @ P^T ----
#pragma unroll
      for (int d = 0; d < 4; ++d) {
        const int row = d * 32 + l31;
        const int swz = row & 7;
#pragma unroll
        for (int sl4 = 0; sl4 < 4; ++sl4) {
          const int seg = (sl4 * 2 + hi) ^ swz;
          v8bf va = *reinterpret_cast<const v8bf*>(Vc + row * 64 + seg * 8);
          acc[d] = __builtin_amdgcn_mfma_f32_32x32x16_bf16(va, pb[sl4].v,
                                                           acc[d], 0, 0, 0);
        }
      }
    }
  }

  // ---- epilogue: normalize, write bf16 (paired 4B stores) ----
  const int b = bh >> 4, head = bh & 15;
  const float inv = 1.0f / l;
#pragma unroll
  for (int d = 0; d < 4; ++d)
#pragma unroll
    for (int q = 0; q < 4; ++q)
#pragma unroll
      for (int rp = 0; rp < 2; ++rp) {
        const int dd = d * 32 + q * 8 + hi * 4 + rp * 2;
        const uint32_t lo16 = f2bf(acc[d][q * 4 + rp * 2] * inv);
        const uint32_t hi16 = f2bf(acc[d][q * 4 + rp * 2 + 1] * inv);
        *reinterpret_cast<uint32_t*>(
            &Ob[((size_t)(b * 2048 + qr)) * 2048 + head * 128 + dd]) =
            lo16 | (hi16 << 16);
      }
}

// ---------------- output projection (fp32 out) ----------------
__global__ __launch_bounds__(256, 2) void out_gemm_kernel(
    const uint16_t* __restrict__ Abf, const uint16_t* __restrict__ Wob,
    float* __restrict__ out) {
  __shared__ uint16_t As[2 * 128 * 64];
  __shared__ uint16_t Bs[2 * 128 * 64];
  const int id  = blockIdx.y * 16 + blockIdx.x;
  const int swz = (id & 7) * 64 + (id >> 3);
  const int m0 = (swz >> 4) * 128, n0 = (swz & 15) * 128;
  v4f acc[4][4];
#pragma unroll
  for (int i = 0; i < 4; ++i)
#pragma unroll
    for (int j = 0; j < 4; ++j) acc[i][j] = (v4f)0.0f;

  gemm128_mainloop(Abf, Wob, m0, n0, As, Bs, acc);

  const int lane = threadIdx.x & 63;
  const int w = threadIdx.x >> 6, wr = w >> 1, wc = w & 1;
  const int lrow = lane & 15, lhi = lane >> 4;
#pragma unroll
  for (int mf = 0; mf < 4; ++mf)
#pragma unroll
    for (int nf = 0; nf < 4; ++nf) {
      const int n = n0 + wc * 64 + nf * 16 + lrow;
#pragma unroll
      for (int r = 0; r < 4; ++r) {
        const int m = m0 + wr * 64 + mf * 16 + lhi * 4 + r;
        out[(size_t)m * 2048 + n] = acc[mf][nf][r];
      }
    }
}

extern "C" void kernel_launch(void* const* d_in, const int* in_sizes, int n_in,
                              void* d_out, int out_size, void* d_ws,
                              size_t ws_size, hipStream_t stream) {
  const float* hidden = (const float*)d_in[0];
  const float* Wq = (const float*)d_in[3];
  const float* Wk = (const float*)d_in[4];
  const float* Wv = (const float*)d_in[5];
  const float* Wo = (const float*)d_in[6];
  const float* cosc = (const float*)d_in[7];
  const float* sinc = (const float*)d_in[8];
  float* out = (float*)d_out;

  uint16_t* Wqb = (uint16_t*)d_ws;
  uint16_t* Wkb = Wqb + 4194304;
  uint16_t* Wvb = Wkb + 4194304;
  uint16_t* Wob = Wvb + 4194304;
  uint16_t* Xbf = Wob + 4194304;
  uint16_t* Qh  = Xbf + 8388608;
  uint16_t* Kh  = Qh + 8388608;
  uint16_t* Vt  = Kh + 8388608;
  uint16_t* Ob  = Xbf;  // X dead after QKV gemm

  cvt_all_kernel<<<dim3(512, 5), 256, 0, stream>>>(
      hidden, Xbf, Wq, Wqb, Wk, Wkb, Wv, Wvb, Wo, Wob);

  qkv_gemm_kernel<<<dim3(16, 32, 3), 256, 0, stream>>>(
      Xbf, Wqb, Wkb, Wvb, cosc, sinc, Qh, Kh, Vt);

  attn_kernel<<<dim3(512), 256, 0, stream>>>(Qh, Kh, Vt, Ob);

  out_gemm_kernel<<<dim3(16, 32), 256, 0, stream>>>(Ob, Wob, out);
}

// Round 5
// 381.226 us; speedup vs baseline: 1.6067x; 1.0725x over previous
//
#include <hip/hip_runtime.h>
#include <cstdint>

// MultiHeadSelfAttention  B=2, T=2048, HIDDEN=2048, NH=16, HD=128 (fp32 io)
// cvt->bf16 -> QKV GEMM(+RoPE, V transposed) -> flash attn -> out-proj GEMM.
// R5: GEMMs use 256x128 tile, 8 waves, 3-deep LDS pipeline with counted
// vmcnt(6) (T3+T4), setprio (T5), XOR-swizzled LDS (T2). Attn uses KVBLK=32
// 3-buf counted-vmcnt(4) pipeline + coalesced O epilogue via LDS bounce.

typedef __bf16 v8bf __attribute__((ext_vector_type(8)));
typedef float  v4f  __attribute__((ext_vector_type(4)));
typedef float  f32x16 __attribute__((ext_vector_type(16)));

__device__ __forceinline__ uint16_t f2bf(float f) {
  union { float f; uint32_t u; } v; v.f = f;
  uint32_t u = v.u;
  return (uint16_t)((u + 0x7FFFu + ((u >> 16) & 1u)) >> 16);  // RNE
}

__device__ __forceinline__ uint32_t cvtpk(float lo, float hi) {
  uint32_t w;
  asm("v_cvt_pk_bf16_f32 %0, %1, %2" : "=v"(w) : "v"(lo), "v"(hi));
  return w;
}

__device__ __forceinline__ void gload16(const void* g, void* l) {
  __builtin_amdgcn_global_load_lds(
      (const __attribute__((address_space(1))) void*)g,
      (__attribute__((address_space(3))) void*)l, 16, 0, 0);
}

// ---------------- fused fp32 -> bf16 conversion (5 tensors) ----------------
__global__ void cvt_all_kernel(const float* __restrict__ s0, uint16_t* d0,
                               const float* __restrict__ s1, uint16_t* d1,
                               const float* __restrict__ s2, uint16_t* d2,
                               const float* __restrict__ s3, uint16_t* d3,
                               const float* __restrict__ s4, uint16_t* d4) {
  const float* src; uint16_t* dst; int n4;
  switch (blockIdx.y) {
    case 0: src = s0; dst = d0; n4 = 2097152; break;
    case 1: src = s1; dst = d1; n4 = 1048576; break;
    case 2: src = s2; dst = d2; n4 = 1048576; break;
    case 3: src = s3; dst = d3; n4 = 1048576; break;
    default: src = s4; dst = d4; n4 = 1048576; break;
  }
  int i = blockIdx.x * blockDim.x + threadIdx.x;
  int stride = gridDim.x * blockDim.x;
  for (; i < n4; i += stride) {
    float4 v = reinterpret_cast<const float4*>(src)[i];
    ushort4 o;
    o.x = f2bf(v.x); o.y = f2bf(v.y); o.z = f2bf(v.z); o.w = f2bf(v.w);
    reinterpret_cast<ushort4*>(dst)[i] = o;
  }
}

// ---- 256x128 GEMM mainloop: 8 waves, 3-deep pipeline, counted vmcnt ----
// As: 3 bufs x [256][64] (96 KB), Bs: 3 bufs x [128][64] (48 KB).
// Per K-tile: 2 phases (ks), each {8 ds_read_b128; 3 gload16; fence;
// barrier; setprio; 16 MFMA; setprio; barrier}. vmcnt(6) at ks=1 only.
__device__ __forceinline__ void gemm256_mainloop(
    const uint16_t* __restrict__ A, const uint16_t* __restrict__ Bt,
    int m0, int n0, uint16_t* As, uint16_t* Bs, v4f acc[4][4]) {
  const int tid  = threadIdx.x;            // 0..511
  const int lane = tid & 63, w = tid >> 6; // 8 waves: 4M x 2N
  const int wm = w >> 1, wn = w & 1;
  const int lrow = lane & 15, lhi = lane >> 4;

  auto stageA = [&](int buf, int k0, int i) {
    int c = i * 512 + tid;                 // 2048 chunks: [256 rows][8 segs]
    int row = c >> 3, seg = c & 7;
    int sseg = seg ^ (row & 7);            // inverse-swizzled global source
    gload16(A + (size_t)(m0 + row) * 2048 + k0 + sseg * 8,
            As + buf * 16384 + c * 8);
  };
  auto stageB = [&](int buf, int k0, int i) {
    int c = i * 512 + tid;                 // 1024 chunks: [128 rows][8 segs]
    int row = c >> 3, seg = c & 7;
    int sseg = seg ^ (row & 7);
    gload16(Bt + (size_t)(n0 + row) * 2048 + k0 + sseg * 8,
            Bs + buf * 8192 + c * 8);
  };

  // prologue: fully stage K-tiles 0 and 1 (12 loads/thread)
#pragma unroll
  for (int i = 0; i < 4; ++i) stageA(0, 0, i);
#pragma unroll
  for (int i = 0; i < 2; ++i) stageB(0, 0, i);
#pragma unroll
  for (int i = 0; i < 4; ++i) stageA(1, 64, i);
#pragma unroll
  for (int i = 0; i < 2; ++i) stageB(1, 64, i);
  asm volatile("s_waitcnt vmcnt(6)" ::: "memory");   // tile0 landed
  __builtin_amdgcn_s_barrier();
  __builtin_amdgcn_sched_barrier(0);

  for (int t = 0; t < 32; ++t) {
    const int cb = t % 3;
    const int sb = (t + 2) % 3;
    const int sk = (t + 2) * 64;
    const uint16_t* Ac = As + cb * 16384;
    const uint16_t* Bc = Bs + cb * 8192;
    const bool do_stage = (t + 2) < 32;
#pragma unroll
    for (int ks = 0; ks < 2; ++ks) {
      v8bf af[4], bfv[4];
#pragma unroll
      for (int mf = 0; mf < 4; ++mf) {
        const int ar = wm * 64 + mf * 16 + lrow;
        const int seg = (ks * 4 + lhi) ^ (ar & 7);
        af[mf] = *reinterpret_cast<const v8bf*>(Ac + ar * 64 + seg * 8);
      }
#pragma unroll
      for (int nf = 0; nf < 4; ++nf) {
        const int br = wn * 64 + nf * 16 + lrow;
        const int seg = (ks * 4 + lhi) ^ (br & 7);
        bfv[nf] = *reinterpret_cast<const v8bf*>(Bc + br * 64 + seg * 8);
      }
      if (do_stage) {
        if (ks == 0) { stageA(sb, sk, 0); stageA(sb, sk, 1); stageB(sb, sk, 0); }
        else         { stageA(sb, sk, 2); stageA(sb, sk, 3); stageB(sb, sk, 1); }
      }
      if (ks == 1) {  // once per K-tile: drain stage(t+1), keep stage(t+2)
        if (t < 30) asm volatile("s_waitcnt vmcnt(6)" ::: "memory");
        else        asm volatile("s_waitcnt vmcnt(0)" ::: "memory");
      } else {
        asm volatile("" ::: "memory");
      }
      __builtin_amdgcn_s_barrier();
      __builtin_amdgcn_sched_barrier(0);
      __builtin_amdgcn_s_setprio(1);
#pragma unroll
      for (int mf = 0; mf < 4; ++mf)
#pragma unroll
        for (int nf = 0; nf < 4; ++nf)
          acc[mf][nf] = __builtin_amdgcn_mfma_f32_16x16x32_bf16(
              af[mf], bfv[nf], acc[mf][nf], 0, 0, 0);
      __builtin_amdgcn_s_setprio(0);
      asm volatile("" ::: "memory");
      __builtin_amdgcn_s_barrier();
      __builtin_amdgcn_sched_barrier(0);
    }
  }
}

// ---------------- QKV projection + RoPE epilogue ----------------
// 768 blocks x 512 thr: 256 blocks per matrix (16 m-tiles x 16 n-tiles).
__global__ __launch_bounds__(512, 2) void qkv_gemm_kernel(
    const uint16_t* __restrict__ Xbf,
    const uint16_t* __restrict__ Wqb, const uint16_t* __restrict__ Wkb,
    const uint16_t* __restrict__ Wvb,
    const float* __restrict__ cosc, const float* __restrict__ sinc,
    uint16_t* __restrict__ Qh, uint16_t* __restrict__ Kh,
    uint16_t* __restrict__ Vt) {
  __shared__ uint16_t As[3 * 256 * 64];
  __shared__ uint16_t Bs[3 * 128 * 64];
  const int id  = blockIdx.x;                    // 768 % 8 == 0, cpx = 96
  const int swz = (id & 7) * 96 + (id >> 3);
  const int which = swz >> 8;
  const int rem = swz & 255;
  const int m0 = (rem >> 4) * 256, n0 = (rem & 15) * 128;
  const uint16_t* Wb = (which == 0) ? Wqb : (which == 1) ? Wkb : Wvb;

  v4f acc[4][4];
#pragma unroll
  for (int i = 0; i < 4; ++i)
#pragma unroll
    for (int j = 0; j < 4; ++j) acc[i][j] = (v4f)0.0f;

  gemm256_mainloop(Xbf, Wb, m0, n0, As, Bs, acc);

  const int lane = threadIdx.x & 63;
  const int w = threadIdx.x >> 6, wm = w >> 1, wn = w & 1;
  const int lrow = lane & 15, lhi = lane >> 4;
  const int b = m0 >> 11;  // tiles never straddle the batch boundary

  if (which < 2) {
    uint16_t* dst = (which == 0) ? Qh : Kh;
#pragma unroll
    for (int mf = 0; mf < 4; ++mf) {
#pragma unroll
      for (int nf = 0; nf < 4; ++nf) {
        const int n = n0 + wn * 64 + nf * 16 + lrow;
        const int head = n >> 7, d = n & 127;
#pragma unroll
        for (int r = 0; r < 4; ++r) {
          const int m = m0 + wm * 64 + mf * 16 + lhi * 4 + r;
          const int t = m & 2047;
          float v = acc[mf][nf][r];
          float p = __shfl_xor(v, 1);
          float rot = (n & 1) ? p : -p;
          float cf = cosc[t * 128 + d], sf = sinc[t * 128 + d];
          dst[((size_t)(b * 16 + head) * 2048 + t) * 128 + d] =
              f2bf(v * cf + rot * sf);
        }
      }
    }
  } else {  // V transposed per head -> Vt[bh][d][t]
#pragma unroll
    for (int mf = 0; mf < 4; ++mf) {
#pragma unroll
      for (int nf = 0; nf < 4; ++nf) {
        const int n = n0 + wn * 64 + nf * 16 + lrow;
        const int head = n >> 7, d = n & 127;
        const int m = m0 + wm * 64 + mf * 16 + lhi * 4;
        const int t = m & 2047;
        ushort4 o;
        o.x = f2bf(acc[mf][nf][0]); o.y = f2bf(acc[mf][nf][1]);
        o.z = f2bf(acc[mf][nf][2]); o.w = f2bf(acc[mf][nf][3]);
        *reinterpret_cast<ushort4*>(
            &Vt[((size_t)(b * 16 + head) * 128 + d) * 2048 + t]) = o;
      }
    }
  }
}

// ---------------- flash attention (swapped QK^T, in-reg softmax) ----------
// 512 blocks x 256 thr (4 waves); block = 128 q-rows; lane owns ONE q-row.
// KVBLK=32, 3 LDS bufs, counted vmcnt(4) pipeline (loads never drain to 0
// mid-loop). Blocks id / id+256 complementary qt -> per-CU balance.
__global__ __launch_bounds__(256, 2) void attn_kernel(
    const uint16_t* __restrict__ Qh, const uint16_t* __restrict__ Kh,
    const uint16_t* __restrict__ Vt, uint16_t* __restrict__ Ob) {
  __shared__ uint16_t KV[3][8192];  // per buf: K[32][128] | V^T[128][32]

  const int id = blockIdx.x;
  const int qt = (id < 256) ? (15 - (id >> 5)) : ((id - 256) >> 5);
  const int bh = id & 31;
  const int tid = threadIdx.x, lane = tid & 63, w = tid >> 6;
  const int l31 = lane & 31, hi = lane >> 5;
  const size_t base = (size_t)bh * 2048 * 128;
  const int q0 = qt * 128 + w * 32;
  const int qr = q0 + l31;

  // Q as persistent B-fragments: qf[ks] = Q[qr][ks*16 + hi*8 .. +8]
  v8bf qf[8];
#pragma unroll
  for (int ks = 0; ks < 8; ++ks)
    qf[ks] = *reinterpret_cast<const v8bf*>(
        Qh + base + (size_t)qr * 128 + ks * 16 + hi * 8);

  f32x16 acc[4];  // O^T: acc[dblk], d = dblk*32 + q*8 + hi*4 + r
#pragma unroll
  for (int d = 0; d < 4; ++d) acc[d] = (f32x16)0.0f;
  float m = -1e30f, l = 0.0f;

  auto stage = [&](int buf, int kt) {
    uint16_t* Kd = KV[buf];
    uint16_t* Vd = KV[buf] + 4096;
#pragma unroll
    for (int i = 0; i < 2; ++i) {        // K tile [32][128], 16 segs/row
      int c = i * 256 + tid;
      int row = c >> 4, seg = c & 15;
      int sseg = seg ^ (row & 7);
      gload16(Kh + base + (size_t)(kt * 32 + row) * 128 + sseg * 8,
              Kd + c * 8);
    }
#pragma unroll
    for (int i = 0; i < 2; ++i) {        // V^T tile [128][32], 4 segs/row
      int c = i * 256 + tid;
      int row = c >> 2, seg = c & 3;
      int sseg = seg ^ (row & 3);
      gload16(Vt + base + (size_t)row * 2048 + kt * 32 + sseg * 8,
              Vd + c * 8);
    }
  };

  const float sc = 0.08838834764831845f;  // 1/sqrt(128)
  const int nkt = 4 * (qt + 1);
  stage(0, 0);
  stage(1, 1);
  for (int kt = 0; kt < nkt; ++kt) {
    const int cb = kt % 3;
    if (kt + 1 < nkt) asm volatile("s_waitcnt vmcnt(4)" ::: "memory");
    else              asm volatile("s_waitcnt vmcnt(0)" ::: "memory");
    __builtin_amdgcn_s_barrier();
    __builtin_amdgcn_sched_barrier(0);
    if (kt + 2 < nkt) stage((kt + 2) % 3, kt + 2);

    if (kt * 32 <= q0 + 31) {            // wave-uniform: any valid kcol?
      const uint16_t* Kc = KV[cb];
      const uint16_t* Vc = KV[cb] + 4096;
      // ---- S^T = K_tile @ Q^T : lane owns qrow qr, 32 kcols ----
      f32x16 s = (f32x16)0.0f;
      {
        const int swzk = l31 & 7;
#pragma unroll
        for (int ks = 0; ks < 8; ++ks) {
          const int seg = (ks * 2 + hi) ^ swzk;
          v8bf kf = *reinterpret_cast<const v8bf*>(Kc + l31 * 128 + seg * 8);
          s = __builtin_amdgcn_mfma_f32_32x32x16_bf16(kf, qf[ks], s, 0, 0, 0);
        }
      }
      // ---- scale + causal mask ----
      if (kt * 32 + 31 > q0) {           // partial tile (wave-uniform)
#pragma unroll
        for (int q = 0; q < 4; ++q)
#pragma unroll
          for (int r = 0; r < 4; ++r) {
            const int kc = kt * 32 + q * 8 + hi * 4 + r;
            float v = s[q * 4 + r] * sc;
            s[q * 4 + r] = (kc > qr) ? -1e30f : v;
          }
      } else {
#pragma unroll
        for (int g = 0; g < 16; ++g) s[g] *= sc;
      }
      // ---- row max (in-register tree + one cross-half shfl) ----
      float t8[8];
#pragma unroll
      for (int g = 0; g < 8; ++g) t8[g] = fmaxf(s[g], s[g + 8]);
      float mx = fmaxf(fmaxf(fmaxf(t8[0], t8[1]), fmaxf(t8[2], t8[3])),
                       fmaxf(fmaxf(t8[4], t8[5]), fmaxf(t8[6], t8[7])));
      mx = fmaxf(mx, __shfl_xor(mx, 32));
      // ---- defer-max rescale (T13, THR=8) ----
      if (!__all(mx - m <= 8.0f)) {
        const float mnew = fmaxf(m, mx);
        const float so = __expf(m - mnew);
        m = mnew;
        l *= so;
#pragma unroll
        for (int d = 0; d < 4; ++d)
#pragma unroll
          for (int g = 0; g < 16; ++g) acc[d][g] *= so;
      }
      // ---- p = exp(s - m), row sum ----
      float rs = 0.0f;
#pragma unroll
      for (int g = 0; g < 16; ++g) {
        const float pv = __expf(s[g] - m);
        s[g] = pv;
        rs += pv;
      }
      rs += __shfl_xor(rs, 32);
      l += rs;
      // ---- pack P -> PV B-fragments (cvt_pk + permlane32_swap) ----
      union BW { uint32_t w[4]; v8bf v; };
      BW pb[2];
#pragma unroll
      for (int sl = 0; sl < 2; ++sl) {
        uint32_t a0 = cvtpk(s[8 * sl + 0], s[8 * sl + 1]);
        uint32_t a1 = cvtpk(s[8 * sl + 2], s[8 * sl + 3]);
        uint32_t b0 = cvtpk(s[8 * sl + 4], s[8 * sl + 5]);
        uint32_t b1 = cvtpk(s[8 * sl + 6], s[8 * sl + 7]);
        asm("v_permlane32_swap_b32 %0, %1" : "+v"(a0), "+v"(b0));
        asm("v_permlane32_swap_b32 %0, %1" : "+v"(a1), "+v"(b1));
        pb[sl].w[0] = a0; pb[sl].w[1] = a1; pb[sl].w[2] = b0; pb[sl].w[3] = b1;
      }
      // ---- O^T += V^T_tile @ P^T ----
      const int swzv = l31 & 3;
#pragma unroll
      for (int d = 0; d < 4; ++d) {
        const int row = d * 32 + l31;
#pragma unroll
        for (int sl = 0; sl < 2; ++sl) {
          const int seg = (sl * 2 + hi) ^ swzv;
          v8bf va = *reinterpret_cast<const v8bf*>(Vc + row * 32 + seg * 8);
          acc[d] = __builtin_amdgcn_mfma_f32_32x32x16_bf16(va, pb[sl].v,
                                                           acc[d], 0, 0, 0);
        }
      }
    }
  }

  // ---- epilogue: normalize, bounce through LDS, coalesced bf16 stores ----
  asm volatile("s_waitcnt vmcnt(0) lgkmcnt(0)" ::: "memory");
  __builtin_amdgcn_s_barrier();
  __builtin_amdgcn_sched_barrier(0);
  uint32_t* L32 = reinterpret_cast<uint32_t*>(&KV[0][0]);
  const float inv = 1.0f / l;
#pragma unroll
  for (int d = 0; d < 4; ++d)
#pragma unroll
    for (int q = 0; q < 4; ++q)
#pragma unroll
      for (int rp = 0; rp < 2; ++rp) {
        const int dd1 = d * 16 + q * 4 + hi * 2 + rp;  // word index 0..63
        const uint32_t lo16 = f2bf(acc[d][q * 4 + rp * 2] * inv);
        const uint32_t hi16 = f2bf(acc[d][q * 4 + rp * 2 + 1] * inv);
        L32[(w * 32 + l31) * 64 + (dd1 ^ ((l31 & 7) << 3))] =
            lo16 | (hi16 << 16);
      }
  asm volatile("" ::: "memory");
  __builtin_amdgcn_s_barrier();
  __builtin_amdgcn_sched_barrier(0);
  const int b = bh >> 4, head = bh & 15;
  uint32_t* Og = reinterpret_cast<uint32_t*>(Ob);
#pragma unroll
  for (int j = 0; j < 32; ++j) {
    const int qrow = qt * 128 + w * 32 + j;
    const uint32_t v = L32[(w * 32 + j) * 64 + (lane ^ ((j & 7) << 3))];
    Og[((size_t)(b * 2048 + qrow) * 2048 + head * 128) / 2 + lane] = v;
  }
}

// ---------------- output projection (fp32 out) ----------------
// 256 blocks x 512 thr: 16 m-tiles x 16 n-tiles.
__global__ __launch_bounds__(512, 2) void out_gemm_kernel(
    const uint16_t* __restrict__ Abf, const uint16_t* __restrict__ Wob,
    float* __restrict__ out) {
  __shared__ uint16_t As[3 * 256 * 64];
  __shared__ uint16_t Bs[3 * 128 * 64];
  const int id  = blockIdx.x;                  // 256 % 8 == 0, cpx = 32
  const int swz = (id & 7) * 32 + (id >> 3);
  const int m0 = (swz >> 4) * 256, n0 = (swz & 15) * 128;
  v4f acc[4][4];
#pragma unroll
  for (int i = 0; i < 4; ++i)
#pragma unroll
    for (int j = 0; j < 4; ++j) acc[i][j] = (v4f)0.0f;

  gemm256_mainloop(Abf, Wob, m0, n0, As, Bs, acc);

  const int lane = threadIdx.x & 63;
  const int w = threadIdx.x >> 6, wm = w >> 1, wn = w & 1;
  const int lrow = lane & 15, lhi = lane >> 4;
#pragma unroll
  for (int mf = 0; mf < 4; ++mf)
#pragma unroll
    for (int nf = 0; nf < 4; ++nf) {
      const int n = n0 + wn * 64 + nf * 16 + lrow;
#pragma unroll
      for (int r = 0; r < 4; ++r) {
        const int m = m0 + wm * 64 + mf * 16 + lhi * 4 + r;
        out[(size_t)m * 2048 + n] = acc[mf][nf][r];
      }
    }
}

extern "C" void kernel_launch(void* const* d_in, const int* in_sizes, int n_in,
                              void* d_out, int out_size, void* d_ws,
                              size_t ws_size, hipStream_t stream) {
  const float* hidden = (const float*)d_in[0];
  const float* Wq = (const float*)d_in[3];
  const float* Wk = (const float*)d_in[4];
  const float* Wv = (const float*)d_in[5];
  const float* Wo = (const float*)d_in[6];
  const float* cosc = (const float*)d_in[7];
  const float* sinc = (const float*)d_in[8];
  float* out = (float*)d_out;

  uint16_t* Wqb = (uint16_t*)d_ws;
  uint16_t* Wkb = Wqb + 4194304;
  uint16_t* Wvb = Wkb + 4194304;
  uint16_t* Wob = Wvb + 4194304;
  uint16_t* Xbf = Wob + 4194304;
  uint16_t* Qh  = Xbf + 8388608;
  uint16_t* Kh  = Qh + 8388608;
  uint16_t* Vt  = Kh + 8388608;
  uint16_t* Ob  = Xbf;  // X dead after QKV gemm

  cvt_all_kernel<<<dim3(512, 5), 256, 0, stream>>>(
      hidden, Xbf, Wq, Wqb, Wk, Wkb, Wv, Wvb, Wo, Wob);

  qkv_gemm_kernel<<<dim3(768), 512, 0, stream>>>(
      Xbf, Wqb, Wkb, Wvb, cosc, sinc, Qh, Kh, Vt);

  attn_kernel<<<dim3(512), 256, 0, stream>>>(Qh, Kh, Vt, Ob);

  out_gemm_kernel<<<dim3(256), 512, 0, stream>>>(Ob, Wob, out);
}